// Round 5
// baseline (1975.010 us; speedup 1.0000x reference)
//
#include <hip/hip_runtime.h>
#include <cmath>

// ---------------- bf16 helpers ----------------
__device__ __forceinline__ float bflo(unsigned int u) {
  union { unsigned int i; float f; } v; v.i = u << 16; return v.f;
}
__device__ __forceinline__ float bfhi(unsigned int u) {
  union { unsigned int i; float f; } v; v.i = u & 0xffff0000u; return v.f;
}
__device__ __forceinline__ float bf2f(unsigned short u) {
  union { unsigned int i; float f; } v; v.i = ((unsigned int)u) << 16; return v.f;
}
__device__ __forceinline__ unsigned short f2bf(float f) {
  union { float f; unsigned int i; } v; v.f = f;
  unsigned int i = v.i;
  return (unsigned short)((i + 0x7fffu + ((i >> 16) & 1u)) >> 16);  // RNE
}

typedef __attribute__((ext_vector_type(8))) short short8;
typedef __attribute__((ext_vector_type(4))) float floatx4;

// ---------------- fp32 -> bf16 weight conversion ----------------
__global__ __launch_bounds__(256) void conv_kernel(
    const float* __restrict__ in, unsigned short* __restrict__ out, int n)
{
  int i = (blockIdx.x * 256 + threadIdx.x) << 2;
  if (i >= n) return;
  float4 v = *reinterpret_cast<const float4*>(in + i);
  ushort4 o;
  o.x = f2bf(v.x); o.y = f2bf(v.y); o.z = f2bf(v.z); o.w = f2bf(v.w);
  *reinterpret_cast<ushort4*>(out + i) = o;
}

// ============ 256x256 8-phase GEMM (KV projection only) ============
// C[M,1024] = A[M,512] @ W[1024,512]^T + bias, bf16 out. M%256==0.
// m201-template structure: 8 waves (2M x 4N), BK=64 as 2 k-halves,
// LDS 128 KiB = 2buf x {A,B} x 2ksub x 16KB. Per K-tile: 4 phases of
// {ds-reads; stage 1 half-tile; barrier; lgkmcnt(0); setprio(1); 16 MFMA;
// setprio(0); barrier}; counted vmcnt(6) only at tile close.
// T2 slot-swizzle key = (row>>1)&3 (R4 post-mortem: key (row&3) left 2-way
// conflicts inside each 8-lane b128 phase -> 5.5M SQ_LDS_BANK_CONFLICT;
// (row>>1)&3 spreads the 8 rows of a phase across all 8 bank groups, the
// same pattern the 128^2 kernel measured at 0 conflicts). Applied BOTH
// sides: pre-swizzled global source + swizzled ds_read.
__global__ __launch_bounds__(512, 2) void gemm256(
    const unsigned short* __restrict__ A,
    const unsigned short* __restrict__ W,
    const float* __restrict__ bias,
    unsigned short* __restrict__ C)
{
  __shared__ __align__(16) unsigned short LA[2][2][8192];
  __shared__ __align__(16) unsigned short LB[2][2][8192];
  const int tid = threadIdx.x;
  const int wave = tid >> 6, lane = tid & 63;
  const int quad = lane >> 4, mrow = lane & 15;
  const int wm = wave >> 2, wn = wave & 3;
  const size_t ldK = 512;
  const int nt = 8;  // K=512 / 64

  // bijective XCD swizzle (nwg=900: q=112, r=4)
  int f = blockIdx.x;
  {
    const int nwg = gridDim.x;
    const int q = nwg >> 3, r = nwg & 7;
    const int x = f & 7, i = f >> 3;
    f = (x < r ? x * (q + 1) : r * (q + 1) + (x - r) * q) + i;
  }
  const int bn = (f & 3) << 8;
  const int bm = (f >> 2) << 8;

  floatx4 acc[8][4];
#pragma unroll
  for (int i = 0; i < 8; ++i)
#pragma unroll
    for (int j = 0; j < 4; ++j) acc[i][j] = (floatx4){0.f, 0.f, 0.f, 0.f};

  // staging coords: row = wave*16 + lane/4 (+128 for 2nd instr); dest slot lane&3.
  // source slot pre-XOR'd with (row>>1)&3 so ds_read at slot quad^((row>>1)&3)
  // returns linear data. +128 preserves (row>>1)&3 (128>>1=64, 64&3=0).
  const int srow0 = (wave << 4) + (lane >> 2);
  const int srow1 = srow0 + 128;
  const int sslot = (lane & 3) ^ ((srow0 >> 1) & 3);

#define STAGEH(dst, srcbase, rowoff, kelem)                                          \
  do {                                                                               \
    __builtin_amdgcn_global_load_lds(                                                \
        (const __attribute__((address_space(1))) unsigned int*)(                     \
            (srcbase) + (size_t)((rowoff) + srow0) * ldK + (kelem) + sslot * 8),     \
        (__attribute__((address_space(3))) unsigned int*)((dst) + wave * 512),       \
        16, 0, 0);                                                                   \
    __builtin_amdgcn_global_load_lds(                                                \
        (const __attribute__((address_space(1))) unsigned int*)(                     \
            (srcbase) + (size_t)((rowoff) + srow1) * ldK + (kelem) + sslot * 8),     \
        (__attribute__((address_space(3))) unsigned int*)((dst) + 4096 + wave * 512),\
        16, 0, 0);                                                                   \
  } while (0)

  // prologue: tile0 all 4 halves -> buf0; tile1 B0,A0,B1 -> buf1 (A1 comes in T0.ph1)
  STAGEH(&LB[0][0][0], W, bn, 0);
  STAGEH(&LA[0][0][0], A, bm, 0);
  STAGEH(&LB[0][1][0], W, bn, 32);
  STAGEH(&LA[0][1][0], A, bm, 32);
  STAGEH(&LB[1][0][0], W, bn, 64);
  STAGEH(&LA[1][0][0], A, bm, 64);
  STAGEH(&LB[1][1][0], W, bn, 96);
  asm volatile("s_waitcnt vmcnt(6)" ::: "memory");
  __builtin_amdgcn_s_barrier();

  // ds_read frag addressing (swizzled slot): off = row*32 + ((quad^((row>>1)&3))*8)
  // row offsets used below are multiples of 16 -> (row>>1)&3 invariant.
  const int rsw = ((quad ^ ((mrow >> 1) & 3)) << 3);
  const int arowb = wm * 128 + mrow;
  const int brows = wn * 64 + mrow;

  for (int T = 0; T < nt; ++T) {
    const int c = T & 1;
    unsigned short* A0 = &LA[c][0][0];
    unsigned short* A1 = &LA[c][1][0];
    unsigned short* B0 = &LB[c][0][0];
    unsigned short* B1 = &LB[c][1][0];
    short8 afr[4], bfr[4];

    // ---- ph1: A0 m0-3 + B0 (k0); stage (T+1).A1 -> other buf (dead since T-1 close)
#pragma unroll
    for (int i = 0; i < 4; ++i)
      afr[i] = *reinterpret_cast<const short8*>(A0 + (arowb + i * 16) * 32 + rsw);
#pragma unroll
    for (int j = 0; j < 4; ++j)
      bfr[j] = *reinterpret_cast<const short8*>(B0 + (brows + j * 16) * 32 + rsw);
    if (T + 1 < nt) STAGEH(&LA[c ^ 1][1][0], A, bm, (T + 1) * 64 + 32);
    __builtin_amdgcn_s_barrier();
    asm volatile("s_waitcnt lgkmcnt(0)" ::: "memory");
    __builtin_amdgcn_s_setprio(1);
#pragma unroll
    for (int i = 0; i < 4; ++i)
#pragma unroll
      for (int j = 0; j < 4; ++j)
        acc[i][j] = __builtin_amdgcn_mfma_f32_16x16x32_bf16(afr[i], bfr[j], acc[i][j], 0, 0, 0);
    __builtin_amdgcn_s_setprio(0);
    __builtin_amdgcn_s_barrier();

    // ---- ph2: A0 m4-7 (B regs reused); stage (T+2).B0 -> this buf (B0 dead after ph1)
#pragma unroll
    for (int i = 0; i < 4; ++i)
      afr[i] = *reinterpret_cast<const short8*>(A0 + (arowb + (i + 4) * 16) * 32 + rsw);
    if (T + 2 < nt) STAGEH(&LB[c][0][0], W, bn, (T + 2) * 64);
    __builtin_amdgcn_s_barrier();
    asm volatile("s_waitcnt lgkmcnt(0)" ::: "memory");
    __builtin_amdgcn_s_setprio(1);
#pragma unroll
    for (int i = 0; i < 4; ++i)
#pragma unroll
      for (int j = 0; j < 4; ++j)
        acc[i + 4][j] = __builtin_amdgcn_mfma_f32_16x16x32_bf16(afr[i], bfr[j], acc[i + 4][j], 0, 0, 0);
    __builtin_amdgcn_s_setprio(0);
    __builtin_amdgcn_s_barrier();

    // ---- ph3: A1 m0-3 + B1 (k1); stage (T+2).A0 -> this buf (A0 dead after ph2)
#pragma unroll
    for (int i = 0; i < 4; ++i)
      afr[i] = *reinterpret_cast<const short8*>(A1 + (arowb + i * 16) * 32 + rsw);
#pragma unroll
    for (int j = 0; j < 4; ++j)
      bfr[j] = *reinterpret_cast<const short8*>(B1 + (brows + j * 16) * 32 + rsw);
    if (T + 2 < nt) STAGEH(&LA[c][0][0], A, bm, (T + 2) * 64);
    __builtin_amdgcn_s_barrier();
    asm volatile("s_waitcnt lgkmcnt(0)" ::: "memory");
    __builtin_amdgcn_s_setprio(1);
#pragma unroll
    for (int i = 0; i < 4; ++i)
#pragma unroll
      for (int j = 0; j < 4; ++j)
        acc[i][j] = __builtin_amdgcn_mfma_f32_16x16x32_bf16(afr[i], bfr[j], acc[i][j], 0, 0, 0);
    __builtin_amdgcn_s_setprio(0);
    __builtin_amdgcn_s_barrier();

    // ---- ph4: A1 m4-7; stage (T+2).B1 -> this buf (B1 dead after ph3);
    //      tile close: counted vmcnt(6) covers next tile's reads.
#pragma unroll
    for (int i = 0; i < 4; ++i)
      afr[i] = *reinterpret_cast<const short8*>(A1 + (arowb + (i + 4) * 16) * 32 + rsw);
    if (T + 2 < nt) STAGEH(&LB[c][1][0], W, bn, (T + 2) * 64 + 32);
    __builtin_amdgcn_s_barrier();
    asm volatile("s_waitcnt lgkmcnt(0)" ::: "memory");
    __builtin_amdgcn_s_setprio(1);
#pragma unroll
    for (int i = 0; i < 4; ++i)
#pragma unroll
      for (int j = 0; j < 4; ++j)
        acc[i + 4][j] = __builtin_amdgcn_mfma_f32_16x16x32_bf16(afr[i], bfr[j], acc[i + 4][j], 0, 0, 0);
    __builtin_amdgcn_s_setprio(0);
    if (T + 2 < nt)
      asm volatile("s_waitcnt vmcnt(6)" ::: "memory");
    else
      asm volatile("s_waitcnt vmcnt(0)" ::: "memory");
    __builtin_amdgcn_s_barrier();
  }
#undef STAGEH

  const int col0 = lane & 15;
  const int row0 = (lane >> 4) << 2;
#pragma unroll
  for (int i = 0; i < 8; ++i)
#pragma unroll
    for (int j = 0; j < 4; ++j) {
      int col = bn + wn * 64 + j * 16 + col0;
      float bv = bias[col];
#pragma unroll
      for (int r = 0; r < 4; ++r) {
        int row = bm + wm * 128 + i * 16 + row0 + r;
        C[(size_t)row * 1024 + col] = f2bf(acc[i][j][r] + bv);
      }
    }
}

// ---------------- MFMA GEMM: C[M,N] = act(A[M,K] @ W[N,K]^T + bias) ----------------
// 128^2 2-phase counted-vmcnt structure; used for all small GEMMs.
__global__ __launch_bounds__(256) void gemm_mfma(
    const unsigned short* __restrict__ A, int lda,
    const unsigned short* __restrict__ W, int ldw,
    const float* __restrict__ bias,
    void* __restrict__ Cv, int ldc,
    int K, int act, int cbf16, int swz)
{
  __shared__ __align__(16) unsigned short As[2][128 * 32];
  __shared__ __align__(16) unsigned short Bs[2][128 * 32];
  const int tid = threadIdx.x;
  const int wave = tid >> 6, lane = tid & 63;

  int bxi = blockIdx.x, byi = blockIdx.y;
  if (swz) {
    int f = byi * gridDim.x + bxi;
    int q = (gridDim.x * gridDim.y) >> 3;
    f = (f & 7) * q + (f >> 3);
    bxi = f % gridDim.x;
    byi = f / gridDim.x;
  }
  const int bm = byi * 128, bn = bxi * 128;
  const int wm = (wave >> 1) << 6, wn = (wave & 1) << 6;

  floatx4 acc[4][4];
#pragma unroll
  for (int i = 0; i < 4; ++i)
#pragma unroll
    for (int j = 0; j < 4; ++j) acc[i][j] = (floatx4){0.f, 0.f, 0.f, 0.f};

  const int srow = (wave << 5) + (lane >> 2);
  const int chsw = (lane & 3) ^ ((srow >> 1) & 3);
  const int scol = chsw << 3;
  const unsigned short* Ag  = A + (size_t)(bm + srow) * lda + scol;
  const unsigned short* Wg  = W + (size_t)(bn + srow) * ldw + scol;
  const unsigned short* Ag2 = Ag + (size_t)16 * lda;
  const unsigned short* Wg2 = Wg + (size_t)16 * ldw;
  const int ldsw = (wave << 5) * 32;

  const int arow = lane & 15;
  const int rsw  = (arow >> 1) & 3;
  const int chrd = (lane >> 4) ^ rsw;
  const int aoff = (wm + arow) * 32 + (chrd << 3);
  const int boff = (wn + arow) * 32 + (chrd << 3);

  const int nt = K >> 5;

#define STAGE(b, t)                                                                 \
  do {                                                                              \
    const int k0_ = (t) << 5;                                                       \
    __builtin_amdgcn_global_load_lds(                                               \
        (const __attribute__((address_space(1))) unsigned int*)(Ag + k0_),          \
        (__attribute__((address_space(3))) unsigned int*)(As[(b)] + ldsw), 16, 0, 0); \
    __builtin_amdgcn_global_load_lds(                                               \
        (const __attribute__((address_space(1))) unsigned int*)(Ag2 + k0_),         \
        (__attribute__((address_space(3))) unsigned int*)(As[(b)] + ldsw + 16 * 32), 16, 0, 0); \
    __builtin_amdgcn_global_load_lds(                                               \
        (const __attribute__((address_space(1))) unsigned int*)(Wg + k0_),          \
        (__attribute__((address_space(3))) unsigned int*)(Bs[(b)] + ldsw), 16, 0, 0); \
    __builtin_amdgcn_global_load_lds(                                               \
        (const __attribute__((address_space(1))) unsigned int*)(Wg2 + k0_),         \
        (__attribute__((address_space(3))) unsigned int*)(Bs[(b)] + ldsw + 16 * 32), 16, 0, 0); \
  } while (0)

  STAGE(0, 0);
  if (nt > 1) STAGE(1, 1);

  int cur = 0;
  for (int t = 0; t < nt; ++t) {
    if (t + 1 < nt) asm volatile("s_waitcnt vmcnt(4)\n\ts_barrier" ::: "memory");
    else            asm volatile("s_waitcnt vmcnt(0)\n\ts_barrier" ::: "memory");

    short8 af[4], bf[4];
#pragma unroll
    for (int i = 0; i < 4; ++i) {
      af[i] = *reinterpret_cast<const short8*>(&As[cur][aoff + (i << 4) * 32]);
      bf[i] = *reinterpret_cast<const short8*>(&Bs[cur][boff + (i << 4) * 32]);
    }
    asm volatile("s_waitcnt lgkmcnt(0)\n\ts_barrier" ::: "memory");
    if (t + 2 < nt) STAGE(cur, t + 2);

#pragma unroll
    for (int i = 0; i < 4; ++i)
#pragma unroll
      for (int j = 0; j < 4; ++j)
        acc[i][j] = __builtin_amdgcn_mfma_f32_16x16x32_bf16(af[i], bf[j], acc[i][j], 0, 0, 0);
    cur ^= 1;
  }
#undef STAGE

  const int col0 = lane & 15;
  const int row0 = (lane >> 4) << 2;
#pragma unroll
  for (int i = 0; i < 4; ++i) {
#pragma unroll
    for (int j = 0; j < 4; ++j) {
      int col = bn + wn + (j << 4) + col0;
      float bv = bias ? bias[col] : 0.f;
#pragma unroll
      for (int r = 0; r < 4; ++r) {
        int row = bm + wm + (i << 4) + row0 + r;
        float v = acc[i][j][r] + bv;
        if (act) v = 0.5f * v * (1.f + erff(v * 0.70710678f));  // exact GELU
        if (cbf16) ((unsigned short*)Cv)[(size_t)row * ldc + col] = f2bf(v);
        else       ((float*)Cv)[(size_t)row * ldc + col] = v;
      }
    }
  }
}

// ---------------- wave reductions ----------------
__device__ __forceinline__ float wred_max(float v) {
#pragma unroll
  for (int off = 32; off > 0; off >>= 1) v = fmaxf(v, __shfl_xor(v, off, 64));
  return v;
}
__device__ __forceinline__ float wred_sum(float v) {
#pragma unroll
  for (int off = 32; off > 0; off >>= 1) v += __shfl_xor(v, off, 64);
  return v;
}

// ============ MFMA cross-attention (flash, 2 k-groups, in-block merge) ============
#define LDK 72
__global__ __launch_bounds__(512) void attn_mfma_kernel(
    const unsigned short* __restrict__ Qp,   // [bg*60][512] bf16
    const unsigned short* __restrict__ KVb,  // [bg*1800][1024] bf16: K|V
    unsigned short* __restrict__ O,          // [bg*60][512] bf16
    const int* __restrict__ tt, const int* __restrict__ ut,
    const unsigned char* __restrict__ km,
    const float* __restrict__ rel)           // rpe[l]: [32][8]
{
  const int bg = blockIdx.x >> 3, h = blockIdx.x & 7;
  const int tid = threadIdx.x;
  const int grp = tid >> 8;
  const int wave = (tid >> 6) & 3;
  const int lane = tid & 63;
  const int quad = lane >> 4, mrow = lane & 15;

  __shared__ __align__(16) unsigned short SMEM[6 * 64 * LDK];
  unsigned short* Ks = SMEM + grp * (3 * 64 * LDK);
  unsigned short* Vt = Ks + 64 * LDK;
  unsigned short* Ps = Vt + 64 * LDK;

  const int qa = wave * 16 + mrow;
  const int qc = qa < 60 ? qa : 59;
  const unsigned short* qptr = Qp + (size_t)(bg * 60 + qc) * 512 + h * 64 + quad * 8;
  const short8 af0 = *reinterpret_cast<const short8*>(qptr);
  const short8 af1 = *reinterpret_cast<const short8*>(qptr + 32);

  const float relreg = rel[(lane & 31) * 8 + h];

  int tq[4];
  float m[4], l[4];
  floatx4 acc[4];
#pragma unroll
  for (int r = 0; r < 4; ++r) {
    int qo = wave * 16 + quad * 4 + r;
    tq[r] = ut[bg * 60 + (qo < 60 ? qo : 59)];
    m[r] = grp ? -1e30f : 0.f;
    l[r] = grp ? 0.f : 1.f;
  }
#pragma unroll
  for (int nt = 0; nt < 4; ++nt) acc[nt] = (floatx4){0.f, 0.f, 0.f, 0.f};

  const int sk = tid & 255;
  const int stok = sk >> 2, schk = sk & 3;

  for (int it = 0; it < 15; ++it) {
    const int k0 = (grp + 2 * it) << 6;
    __syncthreads();
    {
      const int key = k0 + stok;
      uint4 kr0 = {0,0,0,0}, kr1 = {0,0,0,0}, vr0 = {0,0,0,0}, vr1 = {0,0,0,0};
      if (key < 1800) {
        const unsigned short* kb = KVb + ((size_t)bg * 1800 + key) * 1024 + h * 64 + schk * 16;
        kr0 = *reinterpret_cast<const uint4*>(kb);
        kr1 = *reinterpret_cast<const uint4*>(kb + 8);
        vr0 = *reinterpret_cast<const uint4*>(kb + 512);
        vr1 = *reinterpret_cast<const uint4*>(kb + 520);
      }
      *reinterpret_cast<uint4*>(&Ks[stok * LDK + schk * 16]) = kr0;
      *reinterpret_cast<uint4*>(&Ks[stok * LDK + schk * 16 + 8]) = kr1;
      unsigned int wv[8] = {vr0.x, vr0.y, vr0.z, vr0.w, vr1.x, vr1.y, vr1.z, vr1.w};
#pragma unroll
      for (int e = 0; e < 16; ++e)
        Vt[(schk * 16 + e) * LDK + stok] = (unsigned short)(wv[e >> 1] >> ((e & 1) * 16));
    }
    int meta = 0x10000;
    {
      int kk = k0 + lane;
      if (kk < 1800) {
        int base = bg * 1800 + kk;
        meta = tt[base] | (km[base] ? 0x10000 : 0);
      }
    }
    __syncthreads();

    floatx4 S[4];
#pragma unroll
    for (int nt = 0; nt < 4; ++nt) {
      const unsigned short* kb = Ks + (nt * 16 + mrow) * LDK + quad * 8;
      short8 b0 = *reinterpret_cast<const short8*>(kb);
      short8 b1 = *reinterpret_cast<const short8*>(kb + 32);
      floatx4 s = (floatx4){0.f, 0.f, 0.f, 0.f};
      s = __builtin_amdgcn_mfma_f32_16x16x32_bf16(af0, b0, s, 0, 0, 0);
      s = __builtin_amdgcn_mfma_f32_16x16x32_bf16(af1, b1, s, 0, 0, 0);
      S[nt] = s;
    }
    int mcol[4];
#pragma unroll
    for (int nt = 0; nt < 4; ++nt)
      mcol[nt] = __builtin_amdgcn_ds_bpermute((nt * 16 + mrow) << 2, meta);
    float sv[4][4];
#pragma unroll
    for (int nt = 0; nt < 4; ++nt) {
      int tk = mcol[nt] & 0xffff;
      int bad0 = mcol[nt] >> 16;
#pragma unroll
      for (int r = 0; r < 4; ++r) {
        float v = S[nt][r] * 0.125f;
        int ridx = (tq[r] - tk) & 31;
        v += __int_as_float(__builtin_amdgcn_ds_bpermute(ridx << 2, __float_as_int(relreg)));
        sv[nt][r] = (bad0 | (tk >= tq[r])) ? -1e30f : v;
      }
    }
#pragma unroll
    for (int r = 0; r < 4; ++r) {
      float rm = fmaxf(fmaxf(sv[0][r], sv[1][r]), fmaxf(sv[2][r], sv[3][r]));
#pragma unroll
      for (int d = 1; d < 16; d <<= 1) rm = fmaxf(rm, __shfl_xor(rm, d, 64));
      float nm = fmaxf(m[r], rm);
      float corr = __expf(m[r] - nm);
      float ps = 0.f;
      const int prow = (wave * 16 + quad * 4 + r) * LDK + mrow;
#pragma unroll
      for (int nt = 0; nt < 4; ++nt) {
        float p = __expf(sv[nt][r] - nm);
        ps += p;
        Ps[prow + nt * 16] = f2bf(p);
      }
#pragma unroll
      for (int d = 1; d < 16; d <<= 1) ps += __shfl_xor(ps, d, 64);
      l[r] = l[r] * corr + ps;
      m[r] = nm;
#pragma unroll
      for (int nt = 0; nt < 4; ++nt) acc[nt][r] *= corr;
    }
    const unsigned short* pp = Ps + (wave * 16 + mrow) * LDK + quad * 8;
    short8 a0 = *reinterpret_cast<const short8*>(pp);
    short8 a1 = *reinterpret_cast<const short8*>(pp + 32);
#pragma unroll
    for (int nt = 0; nt < 4; ++nt) {
      const unsigned short* vb = Vt + (nt * 16 + mrow) * LDK + quad * 8;
      short8 b0 = *reinterpret_cast<const short8*>(vb);
      short8 b1 = *reinterpret_cast<const short8*>(vb + 32);
      acc[nt] = __builtin_amdgcn_mfma_f32_16x16x32_bf16(a0, b0, acc[nt], 0, 0, 0);
      acc[nt] = __builtin_amdgcn_mfma_f32_16x16x32_bf16(a1, b1, acc[nt], 0, 0, 0);
    }
  }

  __syncthreads();
  float* MA = (float*)SMEM;
  float* Ml = (float*)(SMEM + 64 * 68 * 2);
  float* Ll = Ml + 64;
  if (grp == 1) {
#pragma unroll
    for (int r = 0; r < 4; ++r) {
      int row = wave * 16 + quad * 4 + r;
#pragma unroll
      for (int nt = 0; nt < 4; ++nt)
        MA[row * 68 + nt * 16 + mrow] = acc[nt][r];
      if (mrow == 0) { Ml[row] = m[r]; Ll[row] = l[r]; }
    }
  }
  __syncthreads();
  if (grp == 0) {
#pragma unroll
    for (int r = 0; r < 4; ++r) {
      int row = wave * 16 + quad * 4 + r;
      float m1 = Ml[row], l1 = Ll[row];
      float M = fmaxf(m[r], m1);
      float c0 = __expf(m[r] - M), c1 = __expf(m1 - M);
      float invL = 1.f / (l[r] * c0 + l1 * c1);
      if (row < 60) {
        unsigned short* op = O + (size_t)(bg * 60 + row) * 512 + h * 64;
#pragma unroll
        for (int nt = 0; nt < 4; ++nt) {
          float o = (acc[nt][r] * c0 + MA[row * 68 + nt * 16 + mrow] * c1) * invL;
          op[nt * 16 + mrow] = f2bf(o);
        }
      }
    }
  }
}

// ---------------- VALU flash attention (self-attn, kLen=60) ----------------
#define QPB 32
#define QPW 8
__global__ __launch_bounds__(256) void attn2_kernel(
    const unsigned short* __restrict__ Qp, int qs,
    const unsigned short* __restrict__ Kp, int ks,
    const unsigned short* __restrict__ Vp, int vs,
    unsigned short* __restrict__ O, int os, int kLen,
    const unsigned char* __restrict__ kmask)
{
  const int bg = blockIdx.x >> 3;
  const int h  = blockIdx.x & 7;
  const int q0 = blockIdx.y * QPB;
  const int tid = threadIdx.x;
  const int wave = tid >> 6, lane = tid & 63;

  __shared__ float Qs[QPB][68];
  __shared__ float Ks[64][68];
  __shared__ float Vs[64][68];
  __shared__ float Ps[QPB][68];

  {
    int qr = tid >> 3, j = tid & 7;
    int q = q0 + qr;
    float f[8] = {0, 0, 0, 0, 0, 0, 0, 0};
    if (q < 60) {
      uint4 v = *reinterpret_cast<const uint4*>(Qp + (size_t)(bg * 60 + q) * qs + h * 64 + j * 8);
      f[0] = bflo(v.x); f[1] = bfhi(v.x); f[2] = bflo(v.y); f[3] = bfhi(v.y);
      f[4] = bflo(v.z); f[5] = bfhi(v.z); f[6] = bflo(v.w); f[7] = bfhi(v.w);
    }
#pragma unroll
    for (int e = 0; e < 8; ++e) Qs[qr][j * 8 + e] = f[e];
  }

  float m[QPW], l[QPW], acc[QPW];
#pragma unroll
  for (int i = 0; i < QPW; ++i) { m[i] = 0.f; l[i] = 1.f; acc[i] = 0.f; }

  const int std = tid >> 2;
  const int stj = tid & 3;

  for (int k0 = 0; k0 < kLen; k0 += 64) {
    __syncthreads();
    const bool sok = (k0 + std) < kLen;
    {
      const unsigned short* kb = Kp + ((size_t)bg * kLen + k0 + std) * ks + h * 64 + stj * 16;
      float f[16];
#pragma unroll
      for (int e = 0; e < 16; ++e) f[e] = 0.f;
      if (sok) {
        uint4 v0 = *reinterpret_cast<const uint4*>(kb);
        uint4 v1 = *reinterpret_cast<const uint4*>(kb + 8);
        f[0] = bflo(v0.x); f[1] = bfhi(v0.x); f[2]  = bflo(v0.y); f[3]  = bfhi(v0.y);
        f[4] = bflo(v0.z); f[5] = bfhi(v0.z); f[6]  = bflo(v0.w); f[7]  = bfhi(v0.w);
        f[8] = bflo(v1.x); f[9] = bfhi(v1.x); f[10] = bflo(v1.y); f[11] = bfhi(v1.y);
        f[12] = bflo(v1.z); f[13] = bfhi(v1.z); f[14] = bflo(v1.w); f[15] = bfhi(v1.w);
      }
#pragma unroll
      for (int e = 0; e < 16; ++e) Ks[stj * 16 + e][std] = f[e];
    }
    {
      const unsigned short* vb = Vp + ((size_t)bg * kLen + k0 + std) * vs + h * 64;
#pragma unroll
      for (int c = 0; c < 2; ++c) {
        int off = c * 32 + stj * 8;
        float f[8] = {0, 0, 0, 0, 0, 0, 0, 0};
        if (sok) {
          uint4 v = *reinterpret_cast<const uint4*>(vb + off);
          f[0] = bflo(v.x); f[1] = bfhi(v.x); f[2] = bflo(v.y); f[3] = bfhi(v.y);
          f[4] = bflo(v.z); f[5] = bfhi(v.z); f[6] = bflo(v.w); f[7] = bfhi(v.w);
        }
#pragma unroll
        for (int e = 0; e < 8; ++e) Vs[std][off + e] = f[e];
      }
    }
    const int kk = k0 + lane;
    const bool kok = kk < kLen;
    unsigned char kmv = 0;
    if (kok && kmask) kmv = kmask[(size_t)bg * kLen + kk];
    __syncthreads();

    float s[QPW];
#pragma unroll
    for (int i = 0; i < QPW; ++i) s[i] = 0.f;
    for (int d = 0; d < 64; ++d) {
      float kv = Ks[d][lane];
#pragma unroll
      for (int i = 0; i < QPW; ++i)
        s[i] = fmaf(Qs[wave * QPW + i][d], kv, s[i]);
    }

    const int kmax = min(64, kLen - k0);
#pragma unroll
    for (int i = 0; i < QPW; ++i) {
      float svv = s[i] * 0.125f;
      if (kmv || !kok) svv = -1e30f;
      float nm = fmaxf(m[i], wred_max(svv));
      float p = __expf(svv - nm);
      float ts = wred_sum(p);
      float corr = __expf(m[i] - nm);
      l[i] = l[i] * corr + ts;
      acc[i] *= corr;
      m[i] = nm;
      Ps[wave * QPW + i][lane] = p;
    }
    for (int k = 0; k < kmax; ++k) {
      float v = Vs[k][lane];
#pragma unroll
      for (int i = 0; i < QPW; ++i)
        acc[i] = fmaf(Ps[wave * QPW + i][k], v, acc[i]);
    }
  }

#pragma unroll
  for (int i = 0; i < QPW; ++i) {
    int q = q0 + wave * QPW + i;
    if (q < 60)
      O[(size_t)(bg * 60 + q) * os + h * 64 + lane] = f2bf(acc[i] / l[i]);
  }
}

// ---------------- residual add + LayerNorm (E=512), dual fp32+bf16 out ----------------
__global__ __launch_bounds__(256) void add_ln_kernel(
    const float* __restrict__ a, const float* __restrict__ b,
    const float* __restrict__ g, const float* __restrict__ be,
    float* __restrict__ o, unsigned short* __restrict__ ob)
{
  const int t = blockIdx.x;
  const int tid = threadIdx.x;
  const int wave = tid >> 6, lane = tid & 63;
  const size_t base = (size_t)t * 512;
  float v0 = a[base + tid] + b[base + tid];
  float v1 = a[base + 256 + tid] + b[base + 256 + tid];
  __shared__ float red[4];
  float s = wred_sum(v0 + v1);
  if (lane == 0) red[wave] = s;
  __syncthreads();
  float mean = (red[0] + red[1] + red[2] + red[3]) * (1.0f / 512.0f);
  float d0 = v0 - mean, d1 = v1 - mean;
  float vs = wred_sum(d0 * d0 + d1 * d1);
  __syncthreads();
  if (lane == 0) red[wave] = vs;
  __syncthreads();
  float var = (red[0] + red[1] + red[2] + red[3]) * (1.0f / 512.0f);
  float rstd = rsqrtf(var + 1e-5f);
  float r0 = d0 * rstd * g[tid] + be[tid];
  float r1 = d1 * rstd * g[256 + tid] + be[256 + tid];
  o[base + tid] = r0;
  o[base + 256 + tid] = r1;
  ob[base + tid] = f2bf(r0);
  ob[base + 256 + tid] = f2bf(r1);
}

// ---------------- embedding builders ----------------
__global__ __launch_bounds__(256) void build_traj_kernel(
    const float* __restrict__ tf, const int* __restrict__ ids,
    const float* __restrict__ Ww, unsigned short* __restrict__ traj)
{
  int idx = blockIdx.x * 256 + threadIdx.x;
  int tok = idx >> 9;
  int j = idx & 511;
  float v = (j < 256) ? tf[((size_t)tok << 8) + j] : Ww[(j - 256) * 51 + ids[tok]];
  traj[idx] = f2bf(v);
}

__global__ __launch_bounds__(256) void build_unk_kernel(
    const float* __restrict__ uf, const float* __restrict__ Ww,
    float* __restrict__ x, unsigned short* __restrict__ xb)
{
  int idx = blockIdx.x * 256 + threadIdx.x;
  int tok = idx >> 9;
  int j = idx & 511;
  float v = (j < 256) ? uf[((size_t)tok << 8) + j] : Ww[(j - 256) * 51 + 50];
  x[idx] = v;
  xb[idx] = f2bf(v);
}

// ---------------- final head ----------------
__global__ __launch_bounds__(64) void head_kernel(
    const float* __restrict__ x, const float* __restrict__ Wout, float* __restrict__ out)
{
  const int t = blockIdx.x;
  const int tid = threadIdx.x;
  __shared__ float xs[256];
  for (int i = tid; i < 256; i += 64) xs[i] = x[(size_t)t * 512 + 256 + i];
  __syncthreads();
  if (tid < 51) {
    const float* w = Wout + tid * 256;
    float s = 0.f;
    for (int k = 0; k < 256; ++k) s = fmaf(xs[k], w[k], s);
    out[t * 51 + tid] = s;
  }
}

// ---------------- orchestration ----------------
extern "C" void kernel_launch(void* const* d_in, const int* in_sizes, int n_in,
                              void* d_out, int out_size, void* d_ws, size_t ws_size,
                              hipStream_t stream) {
  const float* tf  = (const float*)d_in[0];
  const float* uf  = (const float*)d_in[1];
  const int*   ids = (const int*)d_in[2];
  const int*   tt  = (const int*)d_in[3];
  const int*   ut  = (const int*)d_in[4];
  const unsigned char* tm = (const unsigned char*)d_in[5];
  const unsigned char* um = (const unsigned char*)d_in[6];
  const float* Ww   = (const float*)d_in[8];
  const float* Wout = (const float*)d_in[9];
  const float* rpe  = (const float*)d_in[10];
  const float* saW  = (const float*)d_in[11];
  const float* sab  = (const float*)d_in[12];
  const float* saO  = (const float*)d_in[13];
  const float* saob = (const float*)d_in[14];
  const float* sag  = (const float*)d_in[15];
  const float* sabn = (const float*)d_in[16];
  const float* caW  = (const float*)d_in[17];
  const float* cab  = (const float*)d_in[18];
  const float* caO  = (const float*)d_in[19];
  const float* caob = (const float*)d_in[20];
  const float* cag  = (const float*)d_in[21];
  const float* cabn = (const float*)d_in[22];
  const float* f1   = (const float*)d_in[23];
  const float* fb1  = (const float*)d_in[24];
  const float* f2   = (const float*)d_in[25];
  const float* fb2  = (const float*)d_in[26];
  const float* fg   = (const float*)d_in[27];
  const float* fbn  = (const float*)d_in[28];

  // ---- workspace layout ----
  unsigned short* trajb = (unsigned short*)d_ws;         // 57600*512 bf16
  unsigned short* KVb   = trajb + (size_t)29491200;      // 57600*1024 bf16 (K|V token-major)
  unsigned short* qkvb  = KVb   + (size_t)58982400;      // 1920*1536 bf16
  unsigned short* hb    = qkvb  + (size_t)2949120;       // 1920*2048 bf16
  unsigned short* xb    = hb    + (size_t)3932160;       // 1920*512 bf16
  float* x    = (float*)(xb + (size_t)983040);           // 1920*512 fp32
  float* ybuf = x + (size_t)983040;                      // 1920*512 fp32
  unsigned short* wtail = (unsigned short*)(ybuf + (size_t)983040);  // byte 200,540,160

  // pre-converted all-layer weights region (48.2 MB) if ws allows; else rotating 2MB scratch
  const size_t NEED = (size_t)200540160 + (size_t)24117248 * 2;   // ~248.8 MB
  const bool pre = ws_size >= NEED;
  unsigned short* wsa  = wtail;                          // 5 x 786432  (sa_Wqkv)
  unsigned short* wsaO = wsa  + (size_t)3932160;         // 5 x 262144  (sa_Wo)
  unsigned short* wca  = wsaO + (size_t)1310720;         // 6 x 786432  (ca_Wqkv)
  unsigned short* wcaO = wca  + (size_t)4718592;         // 6 x 262144  (ca_Wo)
  unsigned short* wf1  = wcaO + (size_t)1572864;         // 6 x 1048576 (ffn_W1)
  unsigned short* wf2  = wf1  + (size_t)6291456;         // 6 x 1048576 (ffn_W2)
  unsigned short* wconv = wtail;                         // fallback rotating scratch (2 MB)

  if (pre) {
    conv_kernel<<<dim3(3840), dim3(256), 0, stream>>>(saW, wsa, 3932160);
    conv_kernel<<<dim3(1280), dim3(256), 0, stream>>>(saO, wsaO, 1310720);
    conv_kernel<<<dim3(4608), dim3(256), 0, stream>>>(caW, wca, 4718592);
    conv_kernel<<<dim3(1536), dim3(256), 0, stream>>>(caO, wcaO, 1572864);
    conv_kernel<<<dim3(6144), dim3(256), 0, stream>>>(f1, wf1, 6291456);
    conv_kernel<<<dim3(6144), dim3(256), 0, stream>>>(f2, wf2, 6291456);
  }

  build_traj_kernel<<<dim3(115200), dim3(256), 0, stream>>>(tf, ids, Ww, trajb);
  build_unk_kernel<<<dim3(3840), dim3(256), 0, stream>>>(uf, Ww, x, xb);

  for (int l = 0; l < 6; ++l) {
    if (l > 0) {
      int sl = l - 1;
      const unsigned short* wq;
      if (pre) wq = wsa + (size_t)sl * 786432;
      else {
        conv_kernel<<<dim3(768), dim3(256), 0, stream>>>(saW + (size_t)sl * 786432, wconv, 786432);
        wq = wconv;
      }
      gemm_mfma<<<dim3(12, 15), dim3(256), 0, stream>>>(
          xb, 512, wq, 512, sab + sl * 1536, qkvb, 1536, 512, 0, 1, 0);
      attn2_kernel<<<dim3(256, 2), dim3(256), 0, stream>>>(
          qkvb, 1536, qkvb + 512, 1536, qkvb + 1024, 1536, hb, 512, 60, um);
      const unsigned short* wo;
      if (pre) wo = wsaO + (size_t)sl * 262144;
      else {
        conv_kernel<<<dim3(256), dim3(256), 0, stream>>>(saO + (size_t)sl * 262144, wconv, 262144);
        wo = wconv;
      }
      gemm_mfma<<<dim3(4, 15), dim3(256), 0, stream>>>(
          hb, 512, wo, 512, saob + sl * 512, ybuf, 512, 512, 0, 0, 0);
      add_ln_kernel<<<dim3(1920), dim3(256), 0, stream>>>(x, ybuf, sag + sl * 512, sabn + sl * 512, x, xb);
    }
    const unsigned short* wqkv;
    if (pre) wqkv = wca + (size_t)l * 786432;
    else {
      conv_kernel<<<dim3(768), dim3(256), 0, stream>>>(caW + (size_t)l * 786432, wconv, 786432);
      wqkv = wconv;
    }
    // cross-attn K|V: [57600,512] @ [1024,512]^T -> [57600,1024] bf16
    // 256^2 8-phase kernel (225 M-tiles x 4 N-tiles = 900 blocks)
    gemm256<<<dim3(900), dim3(512), 0, stream>>>(
        trajb, wqkv + 262144, cab + l * 1536 + 512, KVb);
    // cross-attn Q: [1920,512]
    gemm_mfma<<<dim3(4, 15), dim3(256), 0, stream>>>(
        xb, 512, wqkv, 512, cab + l * 1536, qkvb, 512, 512, 0, 1, 0);
    attn_mfma_kernel<<<dim3(256), dim3(512), 0, stream>>>(
        qkvb, KVb, hb, tt, ut, tm, rpe + l * 256);
    const unsigned short* wco;
    if (pre) wco = wcaO + (size_t)l * 262144;
    else {
      conv_kernel<<<dim3(256), dim3(256), 0, stream>>>(caO + (size_t)l * 262144, wconv, 262144);
      wco = wconv;
    }
    gemm_mfma<<<dim3(4, 15), dim3(256), 0, stream>>>(
        hb, 512, wco, 512, caob + l * 512, ybuf, 512, 512, 0, 0, 0);
    add_ln_kernel<<<dim3(1920), dim3(256), 0, stream>>>(x, ybuf, cag + l * 512, cabn + l * 512, x, xb);
    // FFN1 + exact GELU
    const unsigned short* w1;
    if (pre) w1 = wf1 + (size_t)l * 1048576;
    else {
      conv_kernel<<<dim3(1024), dim3(256), 0, stream>>>(f1 + (size_t)l * 1048576, wconv, 1048576);
      w1 = wconv;
    }
    gemm_mfma<<<dim3(16, 15), dim3(256), 0, stream>>>(
        xb, 512, w1, 512, fb1 + l * 2048, hb, 2048, 512, 1, 1, 0);
    // FFN2
    const unsigned short* w2;
    if (pre) w2 = wf2 + (size_t)l * 1048576;
    else {
      conv_kernel<<<dim3(1024), dim3(256), 0, stream>>>(f2 + (size_t)l * 1048576, wconv, 1048576);
      w2 = wconv;
    }
    gemm_mfma<<<dim3(4, 15), dim3(256), 0, stream>>>(
        hb, 2048, w2, 2048, fb2 + l * 512, ybuf, 512, 2048, 0, 0, 0);
    add_ln_kernel<<<dim3(1920), dim3(256), 0, stream>>>(x, ybuf, fg + l * 512, fbn + l * 512, x, xb);
  }
  head_kernel<<<dim3(1920), dim3(64), 0, stream>>>(x, Wout, (float*)d_out);
}

// Round 6
// 1965.991 us; speedup vs baseline: 1.0046x; 1.0046x over previous
//
#include <hip/hip_runtime.h>
#include <cmath>

// ---------------- bf16 helpers ----------------
__device__ __forceinline__ float bflo(unsigned int u) {
  union { unsigned int i; float f; } v; v.i = u << 16; return v.f;
}
__device__ __forceinline__ float bfhi(unsigned int u) {
  union { unsigned int i; float f; } v; v.i = u & 0xffff0000u; return v.f;
}
__device__ __forceinline__ float bf2f(unsigned short u) {
  union { unsigned int i; float f; } v; v.i = ((unsigned int)u) << 16; return v.f;
}
__device__ __forceinline__ unsigned short f2bf(float f) {
  union { float f; unsigned int i; } v; v.f = f;
  unsigned int i = v.i;
  return (unsigned short)((i + 0x7fffu + ((i >> 16) & 1u)) >> 16);  // RNE
}

typedef __attribute__((ext_vector_type(8))) short short8;
typedef __attribute__((ext_vector_type(4))) float floatx4;

// ---------------- fp32 -> bf16 weight conversion ----------------
__global__ __launch_bounds__(256) void conv_kernel(
    const float* __restrict__ in, unsigned short* __restrict__ out, int n)
{
  int i = (blockIdx.x * 256 + threadIdx.x) << 2;
  if (i >= n) return;
  float4 v = *reinterpret_cast<const float4*>(in + i);
  ushort4 o;
  o.x = f2bf(v.x); o.y = f2bf(v.y); o.z = f2bf(v.z); o.w = f2bf(v.w);
  *reinterpret_cast<ushort4*>(out + i) = o;
}

// ============ 256x256 8-phase GEMM (KV projection only) ============
// C[M,1024] = A[M,512] @ W[1024,512]^T + bias, bf16 out. M%256==0.
// m201-template structure; T2 slot-swizzle key (row>>1)&3 both sides
// (R4 post-mortem), XCD-bijective grid swizzle, counted vmcnt(6).
__global__ __launch_bounds__(512, 2) void gemm256(
    const unsigned short* __restrict__ A,
    const unsigned short* __restrict__ W,
    const float* __restrict__ bias,
    unsigned short* __restrict__ C)
{
  __shared__ __align__(16) unsigned short LA[2][2][8192];
  __shared__ __align__(16) unsigned short LB[2][2][8192];
  const int tid = threadIdx.x;
  const int wave = tid >> 6, lane = tid & 63;
  const int quad = lane >> 4, mrow = lane & 15;
  const int wm = wave >> 2, wn = wave & 3;
  const size_t ldK = 512;
  const int nt = 8;  // K=512 / 64

  // bijective XCD swizzle (nwg=900: q=112, r=4)
  int f = blockIdx.x;
  {
    const int nwg = gridDim.x;
    const int q = nwg >> 3, r = nwg & 7;
    const int x = f & 7, i = f >> 3;
    f = (x < r ? x * (q + 1) : r * (q + 1) + (x - r) * q) + i;
  }
  const int bn = (f & 3) << 8;
  const int bm = (f >> 2) << 8;

  floatx4 acc[8][4];
#pragma unroll
  for (int i = 0; i < 8; ++i)
#pragma unroll
    for (int j = 0; j < 4; ++j) acc[i][j] = (floatx4){0.f, 0.f, 0.f, 0.f};

  const int srow0 = (wave << 4) + (lane >> 2);
  const int srow1 = srow0 + 128;
  const int sslot = (lane & 3) ^ ((srow0 >> 1) & 3);

#define STAGEH(dst, srcbase, rowoff, kelem)                                          \
  do {                                                                               \
    __builtin_amdgcn_global_load_lds(                                                \
        (const __attribute__((address_space(1))) unsigned int*)(                     \
            (srcbase) + (size_t)((rowoff) + srow0) * ldK + (kelem) + sslot * 8),     \
        (__attribute__((address_space(3))) unsigned int*)((dst) + wave * 512),       \
        16, 0, 0);                                                                   \
    __builtin_amdgcn_global_load_lds(                                                \
        (const __attribute__((address_space(1))) unsigned int*)(                     \
            (srcbase) + (size_t)((rowoff) + srow1) * ldK + (kelem) + sslot * 8),     \
        (__attribute__((address_space(3))) unsigned int*)((dst) + 4096 + wave * 512),\
        16, 0, 0);                                                                   \
  } while (0)

  STAGEH(&LB[0][0][0], W, bn, 0);
  STAGEH(&LA[0][0][0], A, bm, 0);
  STAGEH(&LB[0][1][0], W, bn, 32);
  STAGEH(&LA[0][1][0], A, bm, 32);
  STAGEH(&LB[1][0][0], W, bn, 64);
  STAGEH(&LA[1][0][0], A, bm, 64);
  STAGEH(&LB[1][1][0], W, bn, 96);
  asm volatile("s_waitcnt vmcnt(6)" ::: "memory");
  __builtin_amdgcn_s_barrier();

  const int rsw = ((quad ^ ((mrow >> 1) & 3)) << 3);
  const int arowb = wm * 128 + mrow;
  const int brows = wn * 64 + mrow;

  for (int T = 0; T < nt; ++T) {
    const int c = T & 1;
    unsigned short* A0 = &LA[c][0][0];
    unsigned short* A1 = &LA[c][1][0];
    unsigned short* B0 = &LB[c][0][0];
    unsigned short* B1 = &LB[c][1][0];
    short8 afr[4], bfr[4];

    // ---- ph1
#pragma unroll
    for (int i = 0; i < 4; ++i)
      afr[i] = *reinterpret_cast<const short8*>(A0 + (arowb + i * 16) * 32 + rsw);
#pragma unroll
    for (int j = 0; j < 4; ++j)
      bfr[j] = *reinterpret_cast<const short8*>(B0 + (brows + j * 16) * 32 + rsw);
    if (T + 1 < nt) STAGEH(&LA[c ^ 1][1][0], A, bm, (T + 1) * 64 + 32);
    __builtin_amdgcn_s_barrier();
    asm volatile("s_waitcnt lgkmcnt(0)" ::: "memory");
    __builtin_amdgcn_s_setprio(1);
#pragma unroll
    for (int i = 0; i < 4; ++i)
#pragma unroll
      for (int j = 0; j < 4; ++j)
        acc[i][j] = __builtin_amdgcn_mfma_f32_16x16x32_bf16(afr[i], bfr[j], acc[i][j], 0, 0, 0);
    __builtin_amdgcn_s_setprio(0);
    __builtin_amdgcn_s_barrier();

    // ---- ph2
#pragma unroll
    for (int i = 0; i < 4; ++i)
      afr[i] = *reinterpret_cast<const short8*>(A0 + (arowb + (i + 4) * 16) * 32 + rsw);
    if (T + 2 < nt) STAGEH(&LB[c][0][0], W, bn, (T + 2) * 64);
    __builtin_amdgcn_s_barrier();
    asm volatile("s_waitcnt lgkmcnt(0)" ::: "memory");
    __builtin_amdgcn_s_setprio(1);
#pragma unroll
    for (int i = 0; i < 4; ++i)
#pragma unroll
      for (int j = 0; j < 4; ++j)
        acc[i + 4][j] = __builtin_amdgcn_mfma_f32_16x16x32_bf16(afr[i], bfr[j], acc[i + 4][j], 0, 0, 0);
    __builtin_amdgcn_s_setprio(0);
    __builtin_amdgcn_s_barrier();

    // ---- ph3
#pragma unroll
    for (int i = 0; i < 4; ++i)
      afr[i] = *reinterpret_cast<const short8*>(A1 + (arowb + i * 16) * 32 + rsw);
#pragma unroll
    for (int j = 0; j < 4; ++j)
      bfr[j] = *reinterpret_cast<const short8*>(B1 + (brows + j * 16) * 32 + rsw);
    if (T + 2 < nt) STAGEH(&LA[c][0][0], A, bm, (T + 2) * 64);
    __builtin_amdgcn_s_barrier();
    asm volatile("s_waitcnt lgkmcnt(0)" ::: "memory");
    __builtin_amdgcn_s_setprio(1);
#pragma unroll
    for (int i = 0; i < 4; ++i)
#pragma unroll
      for (int j = 0; j < 4; ++j)
        acc[i][j] = __builtin_amdgcn_mfma_f32_16x16x32_bf16(afr[i], bfr[j], acc[i][j], 0, 0, 0);
    __builtin_amdgcn_s_setprio(0);
    __builtin_amdgcn_s_barrier();

    // ---- ph4 (tile close, counted vmcnt)
#pragma unroll
    for (int i = 0; i < 4; ++i)
      afr[i] = *reinterpret_cast<const short8*>(A1 + (arowb + (i + 4) * 16) * 32 + rsw);
    if (T + 2 < nt) STAGEH(&LB[c][1][0], W, bn, (T + 2) * 64 + 32);
    __builtin_amdgcn_s_barrier();
    asm volatile("s_waitcnt lgkmcnt(0)" ::: "memory");
    __builtin_amdgcn_s_setprio(1);
#pragma unroll
    for (int i = 0; i < 4; ++i)
#pragma unroll
      for (int j = 0; j < 4; ++j)
        acc[i + 4][j] = __builtin_amdgcn_mfma_f32_16x16x32_bf16(afr[i], bfr[j], acc[i + 4][j], 0, 0, 0);
    __builtin_amdgcn_s_setprio(0);
    if (T + 2 < nt)
      asm volatile("s_waitcnt vmcnt(6)" ::: "memory");
    else
      asm volatile("s_waitcnt vmcnt(0)" ::: "memory");
    __builtin_amdgcn_s_barrier();
  }
#undef STAGEH

  const int col0 = lane & 15;
  const int row0 = (lane >> 4) << 2;
#pragma unroll
  for (int i = 0; i < 8; ++i)
#pragma unroll
    for (int j = 0; j < 4; ++j) {
      int col = bn + wn * 64 + j * 16 + col0;
      float bv = bias[col];
#pragma unroll
      for (int r = 0; r < 4; ++r) {
        int row = bm + wm * 128 + i * 16 + row0 + r;
        C[(size_t)row * 1024 + col] = f2bf(acc[i][j][r] + bv);
      }
    }
}

// ---------------- MFMA GEMM: C[M,N] = act(A[M,K] @ W[N,K]^T + bias) ----------------
// 128^2 2-phase counted-vmcnt structure; used for all small GEMMs.
__global__ __launch_bounds__(256) void gemm_mfma(
    const unsigned short* __restrict__ A, int lda,
    const unsigned short* __restrict__ W, int ldw,
    const float* __restrict__ bias,
    void* __restrict__ Cv, int ldc,
    int K, int act, int cbf16, int swz)
{
  __shared__ __align__(16) unsigned short As[2][128 * 32];
  __shared__ __align__(16) unsigned short Bs[2][128 * 32];
  const int tid = threadIdx.x;
  const int wave = tid >> 6, lane = tid & 63;

  int bxi = blockIdx.x, byi = blockIdx.y;
  if (swz) {
    int f = byi * gridDim.x + bxi;
    int q = (gridDim.x * gridDim.y) >> 3;
    f = (f & 7) * q + (f >> 3);
    bxi = f % gridDim.x;
    byi = f / gridDim.x;
  }
  const int bm = byi * 128, bn = bxi * 128;
  const int wm = (wave >> 1) << 6, wn = (wave & 1) << 6;

  floatx4 acc[4][4];
#pragma unroll
  for (int i = 0; i < 4; ++i)
#pragma unroll
    for (int j = 0; j < 4; ++j) acc[i][j] = (floatx4){0.f, 0.f, 0.f, 0.f};

  const int srow = (wave << 5) + (lane >> 2);
  const int chsw = (lane & 3) ^ ((srow >> 1) & 3);
  const int scol = chsw << 3;
  const unsigned short* Ag  = A + (size_t)(bm + srow) * lda + scol;
  const unsigned short* Wg  = W + (size_t)(bn + srow) * ldw + scol;
  const unsigned short* Ag2 = Ag + (size_t)16 * lda;
  const unsigned short* Wg2 = Wg + (size_t)16 * ldw;
  const int ldsw = (wave << 5) * 32;

  const int arow = lane & 15;
  const int rsw  = (arow >> 1) & 3;
  const int chrd = (lane >> 4) ^ rsw;
  const int aoff = (wm + arow) * 32 + (chrd << 3);
  const int boff = (wn + arow) * 32 + (chrd << 3);

  const int nt = K >> 5;

#define STAGE(b, t)                                                                 \
  do {                                                                              \
    const int k0_ = (t) << 5;                                                       \
    __builtin_amdgcn_global_load_lds(                                               \
        (const __attribute__((address_space(1))) unsigned int*)(Ag + k0_),          \
        (__attribute__((address_space(3))) unsigned int*)(As[(b)] + ldsw), 16, 0, 0); \
    __builtin_amdgcn_global_load_lds(                                               \
        (const __attribute__((address_space(1))) unsigned int*)(Ag2 + k0_),         \
        (__attribute__((address_space(3))) unsigned int*)(As[(b)] + ldsw + 16 * 32), 16, 0, 0); \
    __builtin_amdgcn_global_load_lds(                                               \
        (const __attribute__((address_space(1))) unsigned int*)(Wg + k0_),          \
        (__attribute__((address_space(3))) unsigned int*)(Bs[(b)] + ldsw), 16, 0, 0); \
    __builtin_amdgcn_global_load_lds(                                               \
        (const __attribute__((address_space(1))) unsigned int*)(Wg2 + k0_),         \
        (__attribute__((address_space(3))) unsigned int*)(Bs[(b)] + ldsw + 16 * 32), 16, 0, 0); \
  } while (0)

  STAGE(0, 0);
  if (nt > 1) STAGE(1, 1);

  int cur = 0;
  for (int t = 0; t < nt; ++t) {
    if (t + 1 < nt) asm volatile("s_waitcnt vmcnt(4)\n\ts_barrier" ::: "memory");
    else            asm volatile("s_waitcnt vmcnt(0)\n\ts_barrier" ::: "memory");

    short8 af[4], bf[4];
#pragma unroll
    for (int i = 0; i < 4; ++i) {
      af[i] = *reinterpret_cast<const short8*>(&As[cur][aoff + (i << 4) * 32]);
      bf[i] = *reinterpret_cast<const short8*>(&Bs[cur][boff + (i << 4) * 32]);
    }
    asm volatile("s_waitcnt lgkmcnt(0)\n\ts_barrier" ::: "memory");
    if (t + 2 < nt) STAGE(cur, t + 2);

#pragma unroll
    for (int i = 0; i < 4; ++i)
#pragma unroll
      for (int j = 0; j < 4; ++j)
        acc[i][j] = __builtin_amdgcn_mfma_f32_16x16x32_bf16(af[i], bf[j], acc[i][j], 0, 0, 0);
    cur ^= 1;
  }
#undef STAGE

  const int col0 = lane & 15;
  const int row0 = (lane >> 4) << 2;
#pragma unroll
  for (int i = 0; i < 4; ++i) {
#pragma unroll
    for (int j = 0; j < 4; ++j) {
      int col = bn + wn + (j << 4) + col0;
      float bv = bias ? bias[col] : 0.f;
#pragma unroll
      for (int r = 0; r < 4; ++r) {
        int row = bm + wm + (i << 4) + row0 + r;
        float v = acc[i][j][r] + bv;
        if (act) v = 0.5f * v * (1.f + erff(v * 0.70710678f));  // exact GELU
        if (cbf16) ((unsigned short*)Cv)[(size_t)row * ldc + col] = f2bf(v);
        else       ((float*)Cv)[(size_t)row * ldc + col] = v;
      }
    }
  }
}

// ---------------- wave reductions ----------------
__device__ __forceinline__ float wred_max(float v) {
#pragma unroll
  for (int off = 32; off > 0; off >>= 1) v = fmaxf(v, __shfl_xor(v, off, 64));
  return v;
}
__device__ __forceinline__ float wred_sum(float v) {
#pragma unroll
  for (int off = 32; off > 0; off >>= 1) v += __shfl_xor(v, off, 64);
  return v;
}

// ============ MFMA cross-attention (flash, 2 k-groups, in-block merge) ============
#define LDK 72
__global__ __launch_bounds__(512) void attn_mfma_kernel(
    const unsigned short* __restrict__ Qp,   // [bg*60][512] bf16
    const unsigned short* __restrict__ KVb,  // [bg*1800][1024] bf16: K|V
    unsigned short* __restrict__ O,          // [bg*60][512] bf16
    const int* __restrict__ tt, const int* __restrict__ ut,
    const unsigned char* __restrict__ km,
    const float* __restrict__ rel)           // rpe[l]: [32][8]
{
  const int bg = blockIdx.x >> 3, h = blockIdx.x & 7;
  const int tid = threadIdx.x;
  const int grp = tid >> 8;
  const int wave = (tid >> 6) & 3;
  const int lane = tid & 63;
  const int quad = lane >> 4, mrow = lane & 15;

  __shared__ __align__(16) unsigned short SMEM[6 * 64 * LDK];
  unsigned short* Ks = SMEM + grp * (3 * 64 * LDK);
  unsigned short* Vt = Ks + 64 * LDK;
  unsigned short* Ps = Vt + 64 * LDK;

  const int qa = wave * 16 + mrow;
  const int qc = qa < 60 ? qa : 59;
  const unsigned short* qptr = Qp + (size_t)(bg * 60 + qc) * 512 + h * 64 + quad * 8;
  const short8 af0 = *reinterpret_cast<const short8*>(qptr);
  const short8 af1 = *reinterpret_cast<const short8*>(qptr + 32);

  const float relreg = rel[(lane & 31) * 8 + h];

  int tq[4];
  float m[4], l[4];
  floatx4 acc[4];
#pragma unroll
  for (int r = 0; r < 4; ++r) {
    int qo = wave * 16 + quad * 4 + r;
    tq[r] = ut[bg * 60 + (qo < 60 ? qo : 59)];
    m[r] = grp ? -1e30f : 0.f;
    l[r] = grp ? 0.f : 1.f;
  }
#pragma unroll
  for (int nt = 0; nt < 4; ++nt) acc[nt] = (floatx4){0.f, 0.f, 0.f, 0.f};

  const int sk = tid & 255;
  const int stok = sk >> 2, schk = sk & 3;

  for (int it = 0; it < 15; ++it) {
    const int k0 = (grp + 2 * it) << 6;
    __syncthreads();
    {
      const int key = k0 + stok;
      uint4 kr0 = {0,0,0,0}, kr1 = {0,0,0,0}, vr0 = {0,0,0,0}, vr1 = {0,0,0,0};
      if (key < 1800) {
        const unsigned short* kb = KVb + ((size_t)bg * 1800 + key) * 1024 + h * 64 + schk * 16;
        kr0 = *reinterpret_cast<const uint4*>(kb);
        kr1 = *reinterpret_cast<const uint4*>(kb + 8);
        vr0 = *reinterpret_cast<const uint4*>(kb + 512);
        vr1 = *reinterpret_cast<const uint4*>(kb + 520);
      }
      *reinterpret_cast<uint4*>(&Ks[stok * LDK + schk * 16]) = kr0;
      *reinterpret_cast<uint4*>(&Ks[stok * LDK + schk * 16 + 8]) = kr1;
      unsigned int wv[8] = {vr0.x, vr0.y, vr0.z, vr0.w, vr1.x, vr1.y, vr1.z, vr1.w};
#pragma unroll
      for (int e = 0; e < 16; ++e)
        Vt[(schk * 16 + e) * LDK + stok] = (unsigned short)(wv[e >> 1] >> ((e & 1) * 16));
    }
    int meta = 0x10000;
    {
      int kk = k0 + lane;
      if (kk < 1800) {
        int base = bg * 1800 + kk;
        meta = tt[base] | (km[base] ? 0x10000 : 0);
      }
    }
    __syncthreads();

    floatx4 S[4];
#pragma unroll
    for (int nt = 0; nt < 4; ++nt) {
      const unsigned short* kb = Ks + (nt * 16 + mrow) * LDK + quad * 8;
      short8 b0 = *reinterpret_cast<const short8*>(kb);
      short8 b1 = *reinterpret_cast<const short8*>(kb + 32);
      floatx4 s = (floatx4){0.f, 0.f, 0.f, 0.f};
      s = __builtin_amdgcn_mfma_f32_16x16x32_bf16(af0, b0, s, 0, 0, 0);
      s = __builtin_amdgcn_mfma_f32_16x16x32_bf16(af1, b1, s, 0, 0, 0);
      S[nt] = s;
    }
    int mcol[4];
#pragma unroll
    for (int nt = 0; nt < 4; ++nt)
      mcol[nt] = __builtin_amdgcn_ds_bpermute((nt * 16 + mrow) << 2, meta);
    float sv[4][4];
#pragma unroll
    for (int nt = 0; nt < 4; ++nt) {
      int tk = mcol[nt] & 0xffff;
      int bad0 = mcol[nt] >> 16;
#pragma unroll
      for (int r = 0; r < 4; ++r) {
        float v = S[nt][r] * 0.125f;
        int ridx = (tq[r] - tk) & 31;
        v += __int_as_float(__builtin_amdgcn_ds_bpermute(ridx << 2, __float_as_int(relreg)));
        sv[nt][r] = (bad0 | (tk >= tq[r])) ? -1e30f : v;
      }
    }
#pragma unroll
    for (int r = 0; r < 4; ++r) {
      float rm = fmaxf(fmaxf(sv[0][r], sv[1][r]), fmaxf(sv[2][r], sv[3][r]));
#pragma unroll
      for (int d = 1; d < 16; d <<= 1) rm = fmaxf(rm, __shfl_xor(rm, d, 64));
      float nm = fmaxf(m[r], rm);
      float corr = __expf(m[r] - nm);
      float ps = 0.f;
      const int prow = (wave * 16 + quad * 4 + r) * LDK + mrow;
#pragma unroll
      for (int nt = 0; nt < 4; ++nt) {
        float p = __expf(sv[nt][r] - nm);
        ps += p;
        Ps[prow + nt * 16] = f2bf(p);
      }
#pragma unroll
      for (int d = 1; d < 16; d <<= 1) ps += __shfl_xor(ps, d, 64);
      l[r] = l[r] * corr + ps;
      m[r] = nm;
#pragma unroll
      for (int nt = 0; nt < 4; ++nt) acc[nt][r] *= corr;
    }
    const unsigned short* pp = Ps + (wave * 16 + mrow) * LDK + quad * 8;
    short8 a0 = *reinterpret_cast<const short8*>(pp);
    short8 a1 = *reinterpret_cast<const short8*>(pp + 32);
#pragma unroll
    for (int nt = 0; nt < 4; ++nt) {
      const unsigned short* vb = Vt + (nt * 16 + mrow) * LDK + quad * 8;
      short8 b0 = *reinterpret_cast<const short8*>(vb);
      short8 b1 = *reinterpret_cast<const short8*>(vb + 32);
      acc[nt] = __builtin_amdgcn_mfma_f32_16x16x32_bf16(a0, b0, acc[nt], 0, 0, 0);
      acc[nt] = __builtin_amdgcn_mfma_f32_16x16x32_bf16(a1, b1, acc[nt], 0, 0, 0);
    }
  }

  __syncthreads();
  float* MA = (float*)SMEM;
  float* Ml = (float*)(SMEM + 64 * 68 * 2);
  float* Ll = Ml + 64;
  if (grp == 1) {
#pragma unroll
    for (int r = 0; r < 4; ++r) {
      int row = wave * 16 + quad * 4 + r;
#pragma unroll
      for (int nt = 0; nt < 4; ++nt)
        MA[row * 68 + nt * 16 + mrow] = acc[nt][r];
      if (mrow == 0) { Ml[row] = m[r]; Ll[row] = l[r]; }
    }
  }
  __syncthreads();
  if (grp == 0) {
#pragma unroll
    for (int r = 0; r < 4; ++r) {
      int row = wave * 16 + quad * 4 + r;
      float m1 = Ml[row], l1 = Ll[row];
      float M = fmaxf(m[r], m1);
      float c0 = __expf(m[r] - M), c1 = __expf(m1 - M);
      float invL = 1.f / (l[r] * c0 + l1 * c1);
      if (row < 60) {
        unsigned short* op = O + (size_t)(bg * 60 + row) * 512 + h * 64;
#pragma unroll
        for (int nt = 0; nt < 4; ++nt) {
          float o = (acc[nt][r] * c0 + MA[row * 68 + nt * 16 + mrow] * c1) * invL;
          op[nt * 16 + mrow] = f2bf(o);
        }
      }
    }
  }
}

// ---------------- VALU flash attention (self-attn, kLen=60) ----------------
#define QPB 32
#define QPW 8
__global__ __launch_bounds__(256) void attn2_kernel(
    const unsigned short* __restrict__ Qp, int qs,
    const unsigned short* __restrict__ Kp, int ks,
    const unsigned short* __restrict__ Vp, int vs,
    unsigned short* __restrict__ O, int os, int kLen,
    const unsigned char* __restrict__ kmask)
{
  const int bg = blockIdx.x >> 3;
  const int h  = blockIdx.x & 7;
  const int q0 = blockIdx.y * QPB;
  const int tid = threadIdx.x;
  const int wave = tid >> 6, lane = tid & 63;

  __shared__ float Qs[QPB][68];
  __shared__ float Ks[64][68];
  __shared__ float Vs[64][68];
  __shared__ float Ps[QPB][68];

  {
    int qr = tid >> 3, j = tid & 7;
    int q = q0 + qr;
    float f[8] = {0, 0, 0, 0, 0, 0, 0, 0};
    if (q < 60) {
      uint4 v = *reinterpret_cast<const uint4*>(Qp + (size_t)(bg * 60 + q) * qs + h * 64 + j * 8);
      f[0] = bflo(v.x); f[1] = bfhi(v.x); f[2] = bflo(v.y); f[3] = bfhi(v.y);
      f[4] = bflo(v.z); f[5] = bfhi(v.z); f[6] = bflo(v.w); f[7] = bfhi(v.w);
    }
#pragma unroll
    for (int e = 0; e < 8; ++e) Qs[qr][j * 8 + e] = f[e];
  }

  float m[QPW], l[QPW], acc[QPW];
#pragma unroll
  for (int i = 0; i < QPW; ++i) { m[i] = 0.f; l[i] = 1.f; acc[i] = 0.f; }

  const int std = tid >> 2;
  const int stj = tid & 3;

  for (int k0 = 0; k0 < kLen; k0 += 64) {
    __syncthreads();
    const bool sok = (k0 + std) < kLen;
    {
      const unsigned short* kb = Kp + ((size_t)bg * kLen + k0 + std) * ks + h * 64 + stj * 16;
      float f[16];
#pragma unroll
      for (int e = 0; e < 16; ++e) f[e] = 0.f;
      if (sok) {
        uint4 v0 = *reinterpret_cast<const uint4*>(kb);
        uint4 v1 = *reinterpret_cast<const uint4*>(kb + 8);
        f[0] = bflo(v0.x); f[1] = bfhi(v0.x); f[2]  = bflo(v0.y); f[3]  = bfhi(v0.y);
        f[4] = bflo(v0.z); f[5] = bfhi(v0.z); f[6]  = bflo(v0.w); f[7]  = bfhi(v0.w);
        f[8] = bflo(v1.x); f[9] = bfhi(v1.x); f[10] = bflo(v1.y); f[11] = bfhi(v1.y);
        f[12] = bflo(v1.z); f[13] = bfhi(v1.z); f[14] = bflo(v1.w); f[15] = bfhi(v1.w);
      }
#pragma unroll
      for (int e = 0; e < 16; ++e) Ks[stj * 16 + e][std] = f[e];
    }
    {
      const unsigned short* vb = Vp + ((size_t)bg * kLen + k0 + std) * vs + h * 64;
#pragma unroll
      for (int c = 0; c < 2; ++c) {
        int off = c * 32 + stj * 8;
        float f[8] = {0, 0, 0, 0, 0, 0, 0, 0};
        if (sok) {
          uint4 v = *reinterpret_cast<const uint4*>(vb + off);
          f[0] = bflo(v.x); f[1] = bfhi(v.x); f[2] = bflo(v.y); f[3] = bfhi(v.y);
          f[4] = bflo(v.z); f[5] = bfhi(v.z); f[6] = bflo(v.w); f[7] = bfhi(v.w);
        }
#pragma unroll
        for (int e = 0; e < 8; ++e) Vs[std][off + e] = f[e];
      }
    }
    const int kk = k0 + lane;
    const bool kok = kk < kLen;
    unsigned char kmv = 0;
    if (kok && kmask) kmv = kmask[(size_t)bg * kLen + kk];
    __syncthreads();

    float s[QPW];
#pragma unroll
    for (int i = 0; i < QPW; ++i) s[i] = 0.f;
    for (int d = 0; d < 64; ++d) {
      float kv = Ks[d][lane];
#pragma unroll
      for (int i = 0; i < QPW; ++i)
        s[i] = fmaf(Qs[wave * QPW + i][d], kv, s[i]);
    }

    const int kmax = min(64, kLen - k0);
#pragma unroll
    for (int i = 0; i < QPW; ++i) {
      float svv = s[i] * 0.125f;
      if (kmv || !kok) svv = -1e30f;
      float nm = fmaxf(m[i], wred_max(svv));
      float p = __expf(svv - nm);
      float ts = wred_sum(p);
      float corr = __expf(m[i] - nm);
      l[i] = l[i] * corr + ts;
      acc[i] *= corr;
      m[i] = nm;
      Ps[wave * QPW + i][lane] = p;
    }
    for (int k = 0; k < kmax; ++k) {
      float v = Vs[k][lane];
#pragma unroll
      for (int i = 0; i < QPW; ++i)
        acc[i] = fmaf(Ps[wave * QPW + i][k], v, acc[i]);
    }
  }

#pragma unroll
  for (int i = 0; i < QPW; ++i) {
    int q = q0 + wave * QPW + i;
    if (q < 60)
      O[(size_t)(bg * 60 + q) * os + h * 64 + lane] = f2bf(acc[i] / l[i]);
  }
}

// ---------------- residual add + LayerNorm (E=512), dual fp32+bf16 out ----------------
__global__ __launch_bounds__(256) void add_ln_kernel(
    const float* __restrict__ a, const float* __restrict__ b,
    const float* __restrict__ g, const float* __restrict__ be,
    float* __restrict__ o, unsigned short* __restrict__ ob)
{
  const int t = blockIdx.x;
  const int tid = threadIdx.x;
  const int wave = tid >> 6, lane = tid & 63;
  const size_t base = (size_t)t * 512;
  float v0 = a[base + tid] + b[base + tid];
  float v1 = a[base + 256 + tid] + b[base + 256 + tid];
  __shared__ float red[4];
  float s = wred_sum(v0 + v1);
  if (lane == 0) red[wave] = s;
  __syncthreads();
  float mean = (red[0] + red[1] + red[2] + red[3]) * (1.0f / 512.0f);
  float d0 = v0 - mean, d1 = v1 - mean;
  float vs = wred_sum(d0 * d0 + d1 * d1);
  __syncthreads();
  if (lane == 0) red[wave] = vs;
  __syncthreads();
  float var = (red[0] + red[1] + red[2] + red[3]) * (1.0f / 512.0f);
  float rstd = rsqrtf(var + 1e-5f);
  float r0 = d0 * rstd * g[tid] + be[tid];
  float r1 = d1 * rstd * g[256 + tid] + be[256 + tid];
  o[base + tid] = r0;
  o[base + 256 + tid] = r1;
  ob[base + tid] = f2bf(r0);
  ob[base + 256 + tid] = f2bf(r1);
}

// ---------------- embedding builders (vectorized: 1 wave = 1 token, 8 elems/thread) ----------------
// token layout: 512 = 256 feat (lanes 0-31, float4 x2 loads) + 256 id-embed
// (lanes 32-63, Ww gather; ids[tok] is wave-uniform broadcast; Ww 52KB L1-fits).
__global__ __launch_bounds__(256) void build_traj_kernel(
    const float* __restrict__ tf, const int* __restrict__ ids,
    const float* __restrict__ Ww, unsigned short* __restrict__ traj)
{
  int idx = blockIdx.x * 256 + threadIdx.x;   // over 57600*64
  int tok = idx >> 6;
  int sub = idx & 63;
  ushort4 o0, o1;
  if (sub < 32) {
    const float* ip = tf + ((size_t)tok << 8) + sub * 8;
    float4 a = *reinterpret_cast<const float4*>(ip);
    float4 b = *reinterpret_cast<const float4*>(ip + 4);
    o0.x = f2bf(a.x); o0.y = f2bf(a.y); o0.z = f2bf(a.z); o0.w = f2bf(a.w);
    o1.x = f2bf(b.x); o1.y = f2bf(b.y); o1.z = f2bf(b.z); o1.w = f2bf(b.w);
  } else {
    int id = ids[tok];
    const float* wp = Ww + (size_t)((sub - 32) * 8) * 51 + id;
    o0.x = f2bf(wp[0]);   o0.y = f2bf(wp[51]);  o0.z = f2bf(wp[102]); o0.w = f2bf(wp[153]);
    o1.x = f2bf(wp[204]); o1.y = f2bf(wp[255]); o1.z = f2bf(wp[306]); o1.w = f2bf(wp[357]);
  }
  unsigned short* op = traj + ((size_t)tok << 9) + sub * 8;
  *reinterpret_cast<ushort4*>(op) = o0;
  *reinterpret_cast<ushort4*>(op + 4) = o1;
}

__global__ __launch_bounds__(256) void build_unk_kernel(
    const float* __restrict__ uf, const float* __restrict__ Ww,
    float* __restrict__ x, unsigned short* __restrict__ xb)
{
  int idx = blockIdx.x * 256 + threadIdx.x;   // over 1920*64
  int tok = idx >> 6;
  int sub = idx & 63;
  float f[8];
  if (sub < 32) {
    const float* ip = uf + ((size_t)tok << 8) + sub * 8;
    float4 a = *reinterpret_cast<const float4*>(ip);
    float4 b = *reinterpret_cast<const float4*>(ip + 4);
    f[0] = a.x; f[1] = a.y; f[2] = a.z; f[3] = a.w;
    f[4] = b.x; f[5] = b.y; f[6] = b.z; f[7] = b.w;
  } else {
    const float* wp = Ww + (size_t)((sub - 32) * 8) * 51 + 50;
#pragma unroll
    for (int e = 0; e < 8; ++e) f[e] = wp[e * 51];
  }
  size_t base = ((size_t)tok << 9) + sub * 8;
  float4 x0 = {f[0], f[1], f[2], f[3]};
  float4 x1 = {f[4], f[5], f[6], f[7]};
  *reinterpret_cast<float4*>(x + base) = x0;
  *reinterpret_cast<float4*>(x + base + 4) = x1;
  ushort4 o0, o1;
  o0.x = f2bf(f[0]); o0.y = f2bf(f[1]); o0.z = f2bf(f[2]); o0.w = f2bf(f[3]);
  o1.x = f2bf(f[4]); o1.y = f2bf(f[5]); o1.z = f2bf(f[6]); o1.w = f2bf(f[7]);
  *reinterpret_cast<ushort4*>(xb + base) = o0;
  *reinterpret_cast<ushort4*>(xb + base + 4) = o1;
}

// ---------------- final head ----------------
__global__ __launch_bounds__(64) void head_kernel(
    const float* __restrict__ x, const float* __restrict__ Wout, float* __restrict__ out)
{
  const int t = blockIdx.x;
  const int tid = threadIdx.x;
  __shared__ float xs[256];
  for (int i = tid; i < 256; i += 64) xs[i] = x[(size_t)t * 512 + 256 + i];
  __syncthreads();
  if (tid < 51) {
    const float* w = Wout + tid * 256;
    float s = 0.f;
    for (int k = 0; k < 256; ++k) s = fmaf(xs[k], w[k], s);
    out[t * 51 + tid] = s;
  }
}

// ---------------- orchestration ----------------
extern "C" void kernel_launch(void* const* d_in, const int* in_sizes, int n_in,
                              void* d_out, int out_size, void* d_ws, size_t ws_size,
                              hipStream_t stream) {
  const float* tf  = (const float*)d_in[0];
  const float* uf  = (const float*)d_in[1];
  const int*   ids = (const int*)d_in[2];
  const int*   tt  = (const int*)d_in[3];
  const int*   ut  = (const int*)d_in[4];
  const unsigned char* tm = (const unsigned char*)d_in[5];
  const unsigned char* um = (const unsigned char*)d_in[6];
  const float* Ww   = (const float*)d_in[8];
  const float* Wout = (const float*)d_in[9];
  const float* rpe  = (const float*)d_in[10];
  const float* saW  = (const float*)d_in[11];
  const float* sab  = (const float*)d_in[12];
  const float* saO  = (const float*)d_in[13];
  const float* saob = (const float*)d_in[14];
  const float* sag  = (const float*)d_in[15];
  const float* sabn = (const float*)d_in[16];
  const float* caW  = (const float*)d_in[17];
  const float* cab  = (const float*)d_in[18];
  const float* caO  = (const float*)d_in[19];
  const float* caob = (const float*)d_in[20];
  const float* cag  = (const float*)d_in[21];
  const float* cabn = (const float*)d_in[22];
  const float* f1   = (const float*)d_in[23];
  const float* fb1  = (const float*)d_in[24];
  const float* f2   = (const float*)d_in[25];
  const float* fb2  = (const float*)d_in[26];
  const float* fg   = (const float*)d_in[27];
  const float* fbn  = (const float*)d_in[28];

  // ---- workspace layout ----
  unsigned short* trajb = (unsigned short*)d_ws;         // 57600*512 bf16
  unsigned short* KVb   = trajb + (size_t)29491200;      // 57600*1024 bf16 (K|V token-major)
  unsigned short* qkvb  = KVb   + (size_t)58982400;      // 1920*1536 bf16
  unsigned short* hb    = qkvb  + (size_t)2949120;       // 1920*2048 bf16
  unsigned short* xb    = hb    + (size_t)3932160;       // 1920*512 bf16
  float* x    = (float*)(xb + (size_t)983040);           // 1920*512 fp32
  float* ybuf = x + (size_t)983040;                      // 1920*512 fp32
  unsigned short* wtail = (unsigned short*)(ybuf + (size_t)983040);  // byte 200,540,160

  // pre-converted all-layer weights region (48.2 MB) if ws allows; else rotating 2MB scratch
  const size_t NEED = (size_t)200540160 + (size_t)24117248 * 2;   // ~248.8 MB
  const bool pre = ws_size >= NEED;
  unsigned short* wsa  = wtail;                          // 5 x 786432  (sa_Wqkv)
  unsigned short* wsaO = wsa  + (size_t)3932160;         // 5 x 262144  (sa_Wo)
  unsigned short* wca  = wsaO + (size_t)1310720;         // 6 x 786432  (ca_Wqkv)
  unsigned short* wcaO = wca  + (size_t)4718592;         // 6 x 262144  (ca_Wo)
  unsigned short* wf1  = wcaO + (size_t)1572864;         // 6 x 1048576 (ffn_W1)
  unsigned short* wf2  = wf1  + (size_t)6291456;         // 6 x 1048576 (ffn_W2)
  unsigned short* wconv = wtail;                         // fallback rotating scratch (2 MB)

  if (pre) {
    conv_kernel<<<dim3(3840), dim3(256), 0, stream>>>(saW, wsa, 3932160);
    conv_kernel<<<dim3(1280), dim3(256), 0, stream>>>(saO, wsaO, 1310720);
    conv_kernel<<<dim3(4608), dim3(256), 0, stream>>>(caW, wca, 4718592);
    conv_kernel<<<dim3(1536), dim3(256), 0, stream>>>(caO, wcaO, 1572864);
    conv_kernel<<<dim3(6144), dim3(256), 0, stream>>>(f1, wf1, 6291456);
    conv_kernel<<<dim3(6144), dim3(256), 0, stream>>>(f2, wf2, 6291456);
  }

  build_traj_kernel<<<dim3(14400), dim3(256), 0, stream>>>(tf, ids, Ww, trajb);
  build_unk_kernel<<<dim3(480), dim3(256), 0, stream>>>(uf, Ww, x, xb);

  for (int l = 0; l < 6; ++l) {
    if (l > 0) {
      int sl = l - 1;
      const unsigned short* wq;
      if (pre) wq = wsa + (size_t)sl * 786432;
      else {
        conv_kernel<<<dim3(768), dim3(256), 0, stream>>>(saW + (size_t)sl * 786432, wconv, 786432);
        wq = wconv;
      }
      gemm_mfma<<<dim3(12, 15), dim3(256), 0, stream>>>(
          xb, 512, wq, 512, sab + sl * 1536, qkvb, 1536, 512, 0, 1, 0);
      attn2_kernel<<<dim3(256, 2), dim3(256), 0, stream>>>(
          qkvb, 1536, qkvb + 512, 1536, qkvb + 1024, 1536, hb, 512, 60, um);
      const unsigned short* wo;
      if (pre) wo = wsaO + (size_t)sl * 262144;
      else {
        conv_kernel<<<dim3(256), dim3(256), 0, stream>>>(saO + (size_t)sl * 262144, wconv, 262144);
        wo = wconv;
      }
      gemm_mfma<<<dim3(4, 15), dim3(256), 0, stream>>>(
          hb, 512, wo, 512, saob + sl * 512, ybuf, 512, 512, 0, 0, 0);
      add_ln_kernel<<<dim3(1920), dim3(256), 0, stream>>>(x, ybuf, sag + sl * 512, sabn + sl * 512, x, xb);
    }
    const unsigned short* wqkv;
    if (pre) wqkv = wca + (size_t)l * 786432;
    else {
      conv_kernel<<<dim3(768), dim3(256), 0, stream>>>(caW + (size_t)l * 786432, wconv, 786432);
      wqkv = wconv;
    }
    // cross-attn K|V: [57600,512] @ [1024,512]^T -> [57600,1024] bf16
    gemm256<<<dim3(900), dim3(512), 0, stream>>>(
        trajb, wqkv + 262144, cab + l * 1536 + 512, KVb);
    // cross-attn Q: [1920,512]
    gemm_mfma<<<dim3(4, 15), dim3(256), 0, stream>>>(
        xb, 512, wqkv, 512, cab + l * 1536, qkvb, 512, 512, 0, 1, 0);
    attn_mfma_kernel<<<dim3(256), dim3(512), 0, stream>>>(
        qkvb, KVb, hb, tt, ut, tm, rpe + l * 256);
    const unsigned short* wco;
    if (pre) wco = wcaO + (size_t)l * 262144;
    else {
      conv_kernel<<<dim3(256), dim3(256), 0, stream>>>(caO + (size_t)l * 262144, wconv, 262144);
      wco = wconv;
    }
    gemm_mfma<<<dim3(4, 15), dim3(256), 0, stream>>>(
        hb, 512, wco, 512, caob + l * 512, ybuf, 512, 512, 0, 0, 0);
    add_ln_kernel<<<dim3(1920), dim3(256), 0, stream>>>(x, ybuf, cag + l * 512, cabn + l * 512, x, xb);
    // FFN1 + exact GELU
    const unsigned short* w1;
    if (pre) w1 = wf1 + (size_t)l * 1048576;
    else {
      conv_kernel<<<dim3(1024), dim3(256), 0, stream>>>(f1 + (size_t)l * 1048576, wconv, 1048576);
      w1 = wconv;
    }
    gemm_mfma<<<dim3(16, 15), dim3(256), 0, stream>>>(
        xb, 512, w1, 512, fb1 + l * 2048, hb, 2048, 512, 1, 1, 0);
    // FFN2
    const unsigned short* w2;
    if (pre) w2 = wf2 + (size_t)l * 1048576;
    else {
      conv_kernel<<<dim3(1024), dim3(256), 0, stream>>>(f2 + (size_t)l * 1048576, wconv, 1048576);
      w2 = wconv;
    }
    gemm_mfma<<<dim3(4, 15), dim3(256), 0, stream>>>(
        hb, 2048, w2, 2048, fb2 + l * 512, ybuf, 512, 2048, 0, 0, 0);
    add_ln_kernel<<<dim3(1920), dim3(256), 0, stream>>>(x, ybuf, fg + l * 512, fbn + l * 512, x, xb);
  }
  head_kernel<<<dim3(1920), dim3(64), 0, stream>>>(x, Wout, (float*)d_out);
}

// Round 7
// 1907.567 us; speedup vs baseline: 1.0354x; 1.0306x over previous
//
#include <hip/hip_runtime.h>
#include <cmath>

// ---------------- bf16 helpers ----------------
__device__ __forceinline__ float bflo(unsigned int u) {
  union { unsigned int i; float f; } v; v.i = u << 16; return v.f;
}
__device__ __forceinline__ float bfhi(unsigned int u) {
  union { unsigned int i; float f; } v; v.i = u & 0xffff0000u; return v.f;
}
__device__ __forceinline__ float bf2f(unsigned short u) {
  union { unsigned int i; float f; } v; v.i = ((unsigned int)u) << 16; return v.f;
}
__device__ __forceinline__ unsigned short f2bf(float f) {
  union { float f; unsigned int i; } v; v.f = f;
  unsigned int i = v.i;
  return (unsigned short)((i + 0x7fffu + ((i >> 16) & 1u)) >> 16);  // RNE
}
__device__ __forceinline__ unsigned int pack2bf(float a, float b) {
  return (unsigned int)f2bf(a) | ((unsigned int)f2bf(b) << 16);
}

typedef __attribute__((ext_vector_type(8))) short short8;
typedef __attribute__((ext_vector_type(4))) float floatx4;

// ---------------- fp32 -> bf16 weight conversion ----------------
__global__ __launch_bounds__(256) void conv_kernel(
    const float* __restrict__ in, unsigned short* __restrict__ out, int n)
{
  int i = (blockIdx.x * 256 + threadIdx.x) << 2;
  if (i >= n) return;
  float4 v = *reinterpret_cast<const float4*>(in + i);
  ushort4 o;
  o.x = f2bf(v.x); o.y = f2bf(v.y); o.z = f2bf(v.z); o.w = f2bf(v.w);
  *reinterpret_cast<ushort4*>(out + i) = o;
}

// ---------------- Ww -> bf16 transposed table Wwt[51][256] (runs once) ----------------
__global__ __launch_bounds__(256) void build_wwt_kernel(
    const float* __restrict__ Ww, unsigned short* __restrict__ Wwt)
{
  int c = blockIdx.x;      // vocab id 0..50
  int r = threadIdx.x;     // embed dim 0..255
  Wwt[c * 256 + r] = f2bf(Ww[r * 51 + c]);
}

// ============ 256x256 8-phase GEMM (KV projection only) ============
// C[M,1024] = A[M,512] @ W[1024,512]^T + bias, bf16 out. M%256==0.
// m201-template structure; T2 slot-swizzle key (row>>1)&3 both sides
// (R4 post-mortem), XCD-bijective grid swizzle, counted vmcnt(6).
__global__ __launch_bounds__(512, 2) void gemm256(
    const unsigned short* __restrict__ A,
    const unsigned short* __restrict__ W,
    const float* __restrict__ bias,
    unsigned short* __restrict__ C)
{
  __shared__ __align__(16) unsigned short LA[2][2][8192];
  __shared__ __align__(16) unsigned short LB[2][2][8192];
  const int tid = threadIdx.x;
  const int wave = tid >> 6, lane = tid & 63;
  const int quad = lane >> 4, mrow = lane & 15;
  const int wm = wave >> 2, wn = wave & 3;
  const size_t ldK = 512;
  const int nt = 8;  // K=512 / 64

  // bijective XCD swizzle (nwg=900: q=112, r=4)
  int f = blockIdx.x;
  {
    const int nwg = gridDim.x;
    const int q = nwg >> 3, r = nwg & 7;
    const int x = f & 7, i = f >> 3;
    f = (x < r ? x * (q + 1) : r * (q + 1) + (x - r) * q) + i;
  }
  const int bn = (f & 3) << 8;
  const int bm = (f >> 2) << 8;

  floatx4 acc[8][4];
#pragma unroll
  for (int i = 0; i < 8; ++i)
#pragma unroll
    for (int j = 0; j < 4; ++j) acc[i][j] = (floatx4){0.f, 0.f, 0.f, 0.f};

  const int srow0 = (wave << 4) + (lane >> 2);
  const int srow1 = srow0 + 128;
  const int sslot = (lane & 3) ^ ((srow0 >> 1) & 3);

#define STAGEH(dst, srcbase, rowoff, kelem)                                          \
  do {                                                                               \
    __builtin_amdgcn_global_load_lds(                                                \
        (const __attribute__((address_space(1))) unsigned int*)(                     \
            (srcbase) + (size_t)((rowoff) + srow0) * ldK + (kelem) + sslot * 8),     \
        (__attribute__((address_space(3))) unsigned int*)((dst) + wave * 512),       \
        16, 0, 0);                                                                   \
    __builtin_amdgcn_global_load_lds(                                                \
        (const __attribute__((address_space(1))) unsigned int*)(                     \
            (srcbase) + (size_t)((rowoff) + srow1) * ldK + (kelem) + sslot * 8),     \
        (__attribute__((address_space(3))) unsigned int*)((dst) + 4096 + wave * 512),\
        16, 0, 0);                                                                   \
  } while (0)

  STAGEH(&LB[0][0][0], W, bn, 0);
  STAGEH(&LA[0][0][0], A, bm, 0);
  STAGEH(&LB[0][1][0], W, bn, 32);
  STAGEH(&LA[0][1][0], A, bm, 32);
  STAGEH(&LB[1][0][0], W, bn, 64);
  STAGEH(&LA[1][0][0], A, bm, 64);
  STAGEH(&LB[1][1][0], W, bn, 96);
  asm volatile("s_waitcnt vmcnt(6)" ::: "memory");
  __builtin_amdgcn_s_barrier();

  const int rsw = ((quad ^ ((mrow >> 1) & 3)) << 3);
  const int arowb = wm * 128 + mrow;
  const int brows = wn * 64 + mrow;

  for (int T = 0; T < nt; ++T) {
    const int c = T & 1;
    unsigned short* A0 = &LA[c][0][0];
    unsigned short* A1 = &LA[c][1][0];
    unsigned short* B0 = &LB[c][0][0];
    unsigned short* B1 = &LB[c][1][0];
    short8 afr[4], bfr[4];

    // ---- ph1
#pragma unroll
    for (int i = 0; i < 4; ++i)
      afr[i] = *reinterpret_cast<const short8*>(A0 + (arowb + i * 16) * 32 + rsw);
#pragma unroll
    for (int j = 0; j < 4; ++j)
      bfr[j] = *reinterpret_cast<const short8*>(B0 + (brows + j * 16) * 32 + rsw);
    if (T + 1 < nt) STAGEH(&LA[c ^ 1][1][0], A, bm, (T + 1) * 64 + 32);
    __builtin_amdgcn_s_barrier();
    asm volatile("s_waitcnt lgkmcnt(0)" ::: "memory");
    __builtin_amdgcn_s_setprio(1);
#pragma unroll
    for (int i = 0; i < 4; ++i)
#pragma unroll
      for (int j = 0; j < 4; ++j)
        acc[i][j] = __builtin_amdgcn_mfma_f32_16x16x32_bf16(afr[i], bfr[j], acc[i][j], 0, 0, 0);
    __builtin_amdgcn_s_setprio(0);
    __builtin_amdgcn_s_barrier();

    // ---- ph2
#pragma unroll
    for (int i = 0; i < 4; ++i)
      afr[i] = *reinterpret_cast<const short8*>(A0 + (arowb + (i + 4) * 16) * 32 + rsw);
    if (T + 2 < nt) STAGEH(&LB[c][0][0], W, bn, (T + 2) * 64);
    __builtin_amdgcn_s_barrier();
    asm volatile("s_waitcnt lgkmcnt(0)" ::: "memory");
    __builtin_amdgcn_s_setprio(1);
#pragma unroll
    for (int i = 0; i < 4; ++i)
#pragma unroll
      for (int j = 0; j < 4; ++j)
        acc[i + 4][j] = __builtin_amdgcn_mfma_f32_16x16x32_bf16(afr[i], bfr[j], acc[i + 4][j], 0, 0, 0);
    __builtin_amdgcn_s_setprio(0);
    __builtin_amdgcn_s_barrier();

    // ---- ph3
#pragma unroll
    for (int i = 0; i < 4; ++i)
      afr[i] = *reinterpret_cast<const short8*>(A1 + (arowb + i * 16) * 32 + rsw);
#pragma unroll
    for (int j = 0; j < 4; ++j)
      bfr[j] = *reinterpret_cast<const short8*>(B1 + (brows + j * 16) * 32 + rsw);
    if (T + 2 < nt) STAGEH(&LA[c][0][0], A, bm, (T + 2) * 64);
    __builtin_amdgcn_s_barrier();
    asm volatile("s_waitcnt lgkmcnt(0)" ::: "memory");
    __builtin_amdgcn_s_setprio(1);
#pragma unroll
    for (int i = 0; i < 4; ++i)
#pragma unroll
      for (int j = 0; j < 4; ++j)
        acc[i][j] = __builtin_amdgcn_mfma_f32_16x16x32_bf16(afr[i], bfr[j], acc[i][j], 0, 0, 0);
    __builtin_amdgcn_s_setprio(0);
    __builtin_amdgcn_s_barrier();

    // ---- ph4 (tile close, counted vmcnt)
#pragma unroll
    for (int i = 0; i < 4; ++i)
      afr[i] = *reinterpret_cast<const short8*>(A1 + (arowb + (i + 4) * 16) * 32 + rsw);
    if (T + 2 < nt) STAGEH(&LB[c][1][0], W, bn, (T + 2) * 64 + 32);
    __builtin_amdgcn_s_barrier();
    asm volatile("s_waitcnt lgkmcnt(0)" ::: "memory");
    __builtin_amdgcn_s_setprio(1);
#pragma unroll
    for (int i = 0; i < 4; ++i)
#pragma unroll
      for (int j = 0; j < 4; ++j)
        acc[i + 4][j] = __builtin_amdgcn_mfma_f32_16x16x32_bf16(afr[i], bfr[j], acc[i + 4][j], 0, 0, 0);
    __builtin_amdgcn_s_setprio(0);
    if (T + 2 < nt)
      asm volatile("s_waitcnt vmcnt(6)" ::: "memory");
    else
      asm volatile("s_waitcnt vmcnt(0)" ::: "memory");
    __builtin_amdgcn_s_barrier();
  }
#undef STAGEH

  const int col0 = lane & 15;
  const int row0 = (lane >> 4) << 2;
#pragma unroll
  for (int i = 0; i < 8; ++i)
#pragma unroll
    for (int j = 0; j < 4; ++j) {
      int col = bn + wn * 64 + j * 16 + col0;
      float bv = bias[col];
#pragma unroll
      for (int r = 0; r < 4; ++r) {
        int row = bm + wm * 128 + i * 16 + row0 + r;
        C[(size_t)row * 1024 + col] = f2bf(acc[i][j][r] + bv);
      }
    }
}

// ---------------- MFMA GEMM: C[M,N] = act(A[M,K] @ W[N,K]^T + bias) ----------------
// 128^2 2-phase counted-vmcnt structure; used for all small GEMMs.
__global__ __launch_bounds__(256) void gemm_mfma(
    const unsigned short* __restrict__ A, int lda,
    const unsigned short* __restrict__ W, int ldw,
    const float* __restrict__ bias,
    void* __restrict__ Cv, int ldc,
    int K, int act, int cbf16, int swz)
{
  __shared__ __align__(16) unsigned short As[2][128 * 32];
  __shared__ __align__(16) unsigned short Bs[2][128 * 32];
  const int tid = threadIdx.x;
  const int wave = tid >> 6, lane = tid & 63;

  int bxi = blockIdx.x, byi = blockIdx.y;
  if (swz) {
    int f = byi * gridDim.x + bxi;
    int q = (gridDim.x * gridDim.y) >> 3;
    f = (f & 7) * q + (f >> 3);
    bxi = f % gridDim.x;
    byi = f / gridDim.x;
  }
  const int bm = byi * 128, bn = bxi * 128;
  const int wm = (wave >> 1) << 6, wn = (wave & 1) << 6;

  floatx4 acc[4][4];
#pragma unroll
  for (int i = 0; i < 4; ++i)
#pragma unroll
    for (int j = 0; j < 4; ++j) acc[i][j] = (floatx4){0.f, 0.f, 0.f, 0.f};

  const int srow = (wave << 5) + (lane >> 2);
  const int chsw = (lane & 3) ^ ((srow >> 1) & 3);
  const int scol = chsw << 3;
  const unsigned short* Ag  = A + (size_t)(bm + srow) * lda + scol;
  const unsigned short* Wg  = W + (size_t)(bn + srow) * ldw + scol;
  const unsigned short* Ag2 = Ag + (size_t)16 * lda;
  const unsigned short* Wg2 = Wg + (size_t)16 * ldw;
  const int ldsw = (wave << 5) * 32;

  const int arow = lane & 15;
  const int rsw  = (arow >> 1) & 3;
  const int chrd = (lane >> 4) ^ rsw;
  const int aoff = (wm + arow) * 32 + (chrd << 3);
  const int boff = (wn + arow) * 32 + (chrd << 3);

  const int nt = K >> 5;

#define STAGE(b, t)                                                                 \
  do {                                                                              \
    const int k0_ = (t) << 5;                                                       \
    __builtin_amdgcn_global_load_lds(                                               \
        (const __attribute__((address_space(1))) unsigned int*)(Ag + k0_),          \
        (__attribute__((address_space(3))) unsigned int*)(As[(b)] + ldsw), 16, 0, 0); \
    __builtin_amdgcn_global_load_lds(                                               \
        (const __attribute__((address_space(1))) unsigned int*)(Ag2 + k0_),         \
        (__attribute__((address_space(3))) unsigned int*)(As[(b)] + ldsw + 16 * 32), 16, 0, 0); \
    __builtin_amdgcn_global_load_lds(                                               \
        (const __attribute__((address_space(1))) unsigned int*)(Wg + k0_),          \
        (__attribute__((address_space(3))) unsigned int*)(Bs[(b)] + ldsw), 16, 0, 0); \
    __builtin_amdgcn_global_load_lds(                                               \
        (const __attribute__((address_space(1))) unsigned int*)(Wg2 + k0_),         \
        (__attribute__((address_space(3))) unsigned int*)(Bs[(b)] + ldsw + 16 * 32), 16, 0, 0); \
  } while (0)

  STAGE(0, 0);
  if (nt > 1) STAGE(1, 1);

  int cur = 0;
  for (int t = 0; t < nt; ++t) {
    if (t + 1 < nt) asm volatile("s_waitcnt vmcnt(4)\n\ts_barrier" ::: "memory");
    else            asm volatile("s_waitcnt vmcnt(0)\n\ts_barrier" ::: "memory");

    short8 af[4], bf[4];
#pragma unroll
    for (int i = 0; i < 4; ++i) {
      af[i] = *reinterpret_cast<const short8*>(&As[cur][aoff + (i << 4) * 32]);
      bf[i] = *reinterpret_cast<const short8*>(&Bs[cur][boff + (i << 4) * 32]);
    }
    asm volatile("s_waitcnt lgkmcnt(0)\n\ts_barrier" ::: "memory");
    if (t + 2 < nt) STAGE(cur, t + 2);

#pragma unroll
    for (int i = 0; i < 4; ++i)
#pragma unroll
      for (int j = 0; j < 4; ++j)
        acc[i][j] = __builtin_amdgcn_mfma_f32_16x16x32_bf16(af[i], bf[j], acc[i][j], 0, 0, 0);
    cur ^= 1;
  }
#undef STAGE

  const int col0 = lane & 15;
  const int row0 = (lane >> 4) << 2;
#pragma unroll
  for (int i = 0; i < 4; ++i) {
#pragma unroll
    for (int j = 0; j < 4; ++j) {
      int col = bn + wn + (j << 4) + col0;
      float bv = bias ? bias[col] : 0.f;
#pragma unroll
      for (int r = 0; r < 4; ++r) {
        int row = bm + wm + (i << 4) + row0 + r;
        float v = acc[i][j][r] + bv;
        if (act) v = 0.5f * v * (1.f + erff(v * 0.70710678f));  // exact GELU
        if (cbf16) ((unsigned short*)Cv)[(size_t)row * ldc + col] = f2bf(v);
        else       ((float*)Cv)[(size_t)row * ldc + col] = v;
      }
    }
  }
}

// ---------------- wave reductions ----------------
__device__ __forceinline__ float wred_max(float v) {
#pragma unroll
  for (int off = 32; off > 0; off >>= 1) v = fmaxf(v, __shfl_xor(v, off, 64));
  return v;
}
__device__ __forceinline__ float wred_sum(float v) {
#pragma unroll
  for (int off = 32; off > 0; off >>= 1) v += __shfl_xor(v, off, 64);
  return v;
}

// ============ MFMA cross-attention (flash, 2 k-groups, in-block merge) ============
#define LDK 72
__global__ __launch_bounds__(512) void attn_mfma_kernel(
    const unsigned short* __restrict__ Qp,   // [bg*60][512] bf16
    const unsigned short* __restrict__ KVb,  // [bg*1800][1024] bf16: K|V
    unsigned short* __restrict__ O,          // [bg*60][512] bf16
    const int* __restrict__ tt, const int* __restrict__ ut,
    const unsigned char* __restrict__ km,
    const float* __restrict__ rel)           // rpe[l]: [32][8]
{
  const int bg = blockIdx.x >> 3, h = blockIdx.x & 7;
  const int tid = threadIdx.x;
  const int grp = tid >> 8;
  const int wave = (tid >> 6) & 3;
  const int lane = tid & 63;
  const int quad = lane >> 4, mrow = lane & 15;

  __shared__ __align__(16) unsigned short SMEM[6 * 64 * LDK];
  unsigned short* Ks = SMEM + grp * (3 * 64 * LDK);
  unsigned short* Vt = Ks + 64 * LDK;
  unsigned short* Ps = Vt + 64 * LDK;

  const int qa = wave * 16 + mrow;
  const int qc = qa < 60 ? qa : 59;
  const unsigned short* qptr = Qp + (size_t)(bg * 60 + qc) * 512 + h * 64 + quad * 8;
  const short8 af0 = *reinterpret_cast<const short8*>(qptr);
  const short8 af1 = *reinterpret_cast<const short8*>(qptr + 32);

  const float relreg = rel[(lane & 31) * 8 + h];

  int tq[4];
  float m[4], l[4];
  floatx4 acc[4];
#pragma unroll
  for (int r = 0; r < 4; ++r) {
    int qo = wave * 16 + quad * 4 + r;
    tq[r] = ut[bg * 60 + (qo < 60 ? qo : 59)];
    m[r] = grp ? -1e30f : 0.f;
    l[r] = grp ? 0.f : 1.f;
  }
#pragma unroll
  for (int nt = 0; nt < 4; ++nt) acc[nt] = (floatx4){0.f, 0.f, 0.f, 0.f};

  const int sk = tid & 255;
  const int stok = sk >> 2, schk = sk & 3;

  for (int it = 0; it < 15; ++it) {
    const int k0 = (grp + 2 * it) << 6;
    __syncthreads();
    {
      const int key = k0 + stok;
      uint4 kr0 = {0,0,0,0}, kr1 = {0,0,0,0}, vr0 = {0,0,0,0}, vr1 = {0,0,0,0};
      if (key < 1800) {
        const unsigned short* kb = KVb + ((size_t)bg * 1800 + key) * 1024 + h * 64 + schk * 16;
        kr0 = *reinterpret_cast<const uint4*>(kb);
        kr1 = *reinterpret_cast<const uint4*>(kb + 8);
        vr0 = *reinterpret_cast<const uint4*>(kb + 512);
        vr1 = *reinterpret_cast<const uint4*>(kb + 520);
      }
      *reinterpret_cast<uint4*>(&Ks[stok * LDK + schk * 16]) = kr0;
      *reinterpret_cast<uint4*>(&Ks[stok * LDK + schk * 16 + 8]) = kr1;
      unsigned int wv[8] = {vr0.x, vr0.y, vr0.z, vr0.w, vr1.x, vr1.y, vr1.z, vr1.w};
#pragma unroll
      for (int e = 0; e < 16; ++e)
        Vt[(schk * 16 + e) * LDK + stok] = (unsigned short)(wv[e >> 1] >> ((e & 1) * 16));
    }
    int meta = 0x10000;
    {
      int kk = k0 + lane;
      if (kk < 1800) {
        int base = bg * 1800 + kk;
        meta = tt[base] | (km[base] ? 0x10000 : 0);
      }
    }
    __syncthreads();

    floatx4 S[4];
#pragma unroll
    for (int nt = 0; nt < 4; ++nt) {
      const unsigned short* kb = Ks + (nt * 16 + mrow) * LDK + quad * 8;
      short8 b0 = *reinterpret_cast<const short8*>(kb);
      short8 b1 = *reinterpret_cast<const short8*>(kb + 32);
      floatx4 s = (floatx4){0.f, 0.f, 0.f, 0.f};
      s = __builtin_amdgcn_mfma_f32_16x16x32_bf16(af0, b0, s, 0, 0, 0);
      s = __builtin_amdgcn_mfma_f32_16x16x32_bf16(af1, b1, s, 0, 0, 0);
      S[nt] = s;
    }
    int mcol[4];
#pragma unroll
    for (int nt = 0; nt < 4; ++nt)
      mcol[nt] = __builtin_amdgcn_ds_bpermute((nt * 16 + mrow) << 2, meta);
    float sv[4][4];
#pragma unroll
    for (int nt = 0; nt < 4; ++nt) {
      int tk = mcol[nt] & 0xffff;
      int bad0 = mcol[nt] >> 16;
#pragma unroll
      for (int r = 0; r < 4; ++r) {
        float v = S[nt][r] * 0.125f;
        int ridx = (tq[r] - tk) & 31;
        v += __int_as_float(__builtin_amdgcn_ds_bpermute(ridx << 2, __float_as_int(relreg)));
        sv[nt][r] = (bad0 | (tk >= tq[r])) ? -1e30f : v;
      }
    }
#pragma unroll
    for (int r = 0; r < 4; ++r) {
      float rm = fmaxf(fmaxf(sv[0][r], sv[1][r]), fmaxf(sv[2][r], sv[3][r]));
#pragma unroll
      for (int d = 1; d < 16; d <<= 1) rm = fmaxf(rm, __shfl_xor(rm, d, 64));
      float nm = fmaxf(m[r], rm);
      float corr = __expf(m[r] - nm);
      float ps = 0.f;
      const int prow = (wave * 16 + quad * 4 + r) * LDK + mrow;
#pragma unroll
      for (int nt = 0; nt < 4; ++nt) {
        float p = __expf(sv[nt][r] - nm);
        ps += p;
        Ps[prow + nt * 16] = f2bf(p);
      }
#pragma unroll
      for (int d = 1; d < 16; d <<= 1) ps += __shfl_xor(ps, d, 64);
      l[r] = l[r] * corr + ps;
      m[r] = nm;
#pragma unroll
      for (int nt = 0; nt < 4; ++nt) acc[nt][r] *= corr;
    }
    const unsigned short* pp = Ps + (wave * 16 + mrow) * LDK + quad * 8;
    short8 a0 = *reinterpret_cast<const short8*>(pp);
    short8 a1 = *reinterpret_cast<const short8*>(pp + 32);
#pragma unroll
    for (int nt = 0; nt < 4; ++nt) {
      const unsigned short* vb = Vt + (nt * 16 + mrow) * LDK + quad * 8;
      short8 b0 = *reinterpret_cast<const short8*>(vb);
      short8 b1 = *reinterpret_cast<const short8*>(vb + 32);
      acc[nt] = __builtin_amdgcn_mfma_f32_16x16x32_bf16(a0, b0, acc[nt], 0, 0, 0);
      acc[nt] = __builtin_amdgcn_mfma_f32_16x16x32_bf16(a1, b1, acc[nt], 0, 0, 0);
    }
  }

  __syncthreads();
  float* MA = (float*)SMEM;
  float* Ml = (float*)(SMEM + 64 * 68 * 2);
  float* Ll = Ml + 64;
  if (grp == 1) {
#pragma unroll
    for (int r = 0; r < 4; ++r) {
      int row = wave * 16 + quad * 4 + r;
#pragma unroll
      for (int nt = 0; nt < 4; ++nt)
        MA[row * 68 + nt * 16 + mrow] = acc[nt][r];
      if (mrow == 0) { Ml[row] = m[r]; Ll[row] = l[r]; }
    }
  }
  __syncthreads();
  if (grp == 0) {
#pragma unroll
    for (int r = 0; r < 4; ++r) {
      int row = wave * 16 + quad * 4 + r;
      float m1 = Ml[row], l1 = Ll[row];
      float M = fmaxf(m[r], m1);
      float c0 = __expf(m[r] - M), c1 = __expf(m1 - M);
      float invL = 1.f / (l[r] * c0 + l1 * c1);
      if (row < 60) {
        unsigned short* op = O + (size_t)(bg * 60 + row) * 512 + h * 64;
#pragma unroll
        for (int nt = 0; nt < 4; ++nt) {
          float o = (acc[nt][r] * c0 + MA[row * 68 + nt * 16 + mrow] * c1) * invL;
          op[nt * 16 + mrow] = f2bf(o);
        }
      }
    }
  }
}

// ---------------- VALU flash attention (self-attn, kLen=60) ----------------
#define QPB 32
#define QPW 8
__global__ __launch_bounds__(256) void attn2_kernel(
    const unsigned short* __restrict__ Qp, int qs,
    const unsigned short* __restrict__ Kp, int ks,
    const unsigned short* __restrict__ Vp, int vs,
    unsigned short* __restrict__ O, int os, int kLen,
    const unsigned char* __restrict__ kmask)
{
  const int bg = blockIdx.x >> 3;
  const int h  = blockIdx.x & 7;
  const int q0 = blockIdx.y * QPB;
  const int tid = threadIdx.x;
  const int wave = tid >> 6, lane = tid & 63;

  __shared__ float Qs[QPB][68];
  __shared__ float Ks[64][68];
  __shared__ float Vs[64][68];
  __shared__ float Ps[QPB][68];

  {
    int qr = tid >> 3, j = tid & 7;
    int q = q0 + qr;
    float f[8] = {0, 0, 0, 0, 0, 0, 0, 0};
    if (q < 60) {
      uint4 v = *reinterpret_cast<const uint4*>(Qp + (size_t)(bg * 60 + q) * qs + h * 64 + j * 8);
      f[0] = bflo(v.x); f[1] = bfhi(v.x); f[2] = bflo(v.y); f[3] = bfhi(v.y);
      f[4] = bflo(v.z); f[5] = bfhi(v.z); f[6] = bflo(v.w); f[7] = bfhi(v.w);
    }
#pragma unroll
    for (int e = 0; e < 8; ++e) Qs[qr][j * 8 + e] = f[e];
  }

  float m[QPW], l[QPW], acc[QPW];
#pragma unroll
  for (int i = 0; i < QPW; ++i) { m[i] = 0.f; l[i] = 1.f; acc[i] = 0.f; }

  const int std = tid >> 2;
  const int stj = tid & 3;

  for (int k0 = 0; k0 < kLen; k0 += 64) {
    __syncthreads();
    const bool sok = (k0 + std) < kLen;
    {
      const unsigned short* kb = Kp + ((size_t)bg * kLen + k0 + std) * ks + h * 64 + stj * 16;
      float f[16];
#pragma unroll
      for (int e = 0; e < 16; ++e) f[e] = 0.f;
      if (sok) {
        uint4 v0 = *reinterpret_cast<const uint4*>(kb);
        uint4 v1 = *reinterpret_cast<const uint4*>(kb + 8);
        f[0] = bflo(v0.x); f[1] = bfhi(v0.x); f[2]  = bflo(v0.y); f[3]  = bfhi(v0.y);
        f[4] = bflo(v0.z); f[5] = bfhi(v0.z); f[6]  = bflo(v0.w); f[7]  = bfhi(v0.w);
        f[8] = bflo(v1.x); f[9] = bfhi(v1.x); f[10] = bflo(v1.y); f[11] = bfhi(v1.y);
        f[12] = bflo(v1.z); f[13] = bfhi(v1.z); f[14] = bflo(v1.w); f[15] = bfhi(v1.w);
      }
#pragma unroll
      for (int e = 0; e < 16; ++e) Ks[stj * 16 + e][std] = f[e];
    }
    {
      const unsigned short* vb = Vp + ((size_t)bg * kLen + k0 + std) * vs + h * 64;
#pragma unroll
      for (int c = 0; c < 2; ++c) {
        int off = c * 32 + stj * 8;
        float f[8] = {0, 0, 0, 0, 0, 0, 0, 0};
        if (sok) {
          uint4 v = *reinterpret_cast<const uint4*>(vb + off);
          f[0] = bflo(v.x); f[1] = bfhi(v.x); f[2] = bflo(v.y); f[3] = bfhi(v.y);
          f[4] = bflo(v.z); f[5] = bfhi(v.z); f[6] = bflo(v.w); f[7] = bfhi(v.w);
        }
#pragma unroll
        for (int e = 0; e < 8; ++e) Vs[std][off + e] = f[e];
      }
    }
    const int kk = k0 + lane;
    const bool kok = kk < kLen;
    unsigned char kmv = 0;
    if (kok && kmask) kmv = kmask[(size_t)bg * kLen + kk];
    __syncthreads();

    float s[QPW];
#pragma unroll
    for (int i = 0; i < QPW; ++i) s[i] = 0.f;
    for (int d = 0; d < 64; ++d) {
      float kv = Ks[d][lane];
#pragma unroll
      for (int i = 0; i < QPW; ++i)
        s[i] = fmaf(Qs[wave * QPW + i][d], kv, s[i]);
    }

    const int kmax = min(64, kLen - k0);
#pragma unroll
    for (int i = 0; i < QPW; ++i) {
      float svv = s[i] * 0.125f;
      if (kmv || !kok) svv = -1e30f;
      float nm = fmaxf(m[i], wred_max(svv));
      float p = __expf(svv - nm);
      float ts = wred_sum(p);
      float corr = __expf(m[i] - nm);
      l[i] = l[i] * corr + ts;
      acc[i] *= corr;
      m[i] = nm;
      Ps[wave * QPW + i][lane] = p;
    }
    for (int k = 0; k < kmax; ++k) {
      float v = Vs[k][lane];
#pragma unroll
      for (int i = 0; i < QPW; ++i)
        acc[i] = fmaf(Ps[wave * QPW + i][k], v, acc[i]);
    }
  }

#pragma unroll
  for (int i = 0; i < QPW; ++i) {
    int q = q0 + wave * QPW + i;
    if (q < 60)
      O[(size_t)(bg * 60 + q) * os + h * 64 + lane] = f2bf(acc[i] / l[i]);
  }
}

// ---------------- residual add + LayerNorm (E=512), dual fp32+bf16 out ----------------
__global__ __launch_bounds__(256) void add_ln_kernel(
    const float* __restrict__ a, const float* __restrict__ b,
    const float* __restrict__ g, const float* __restrict__ be,
    float* __restrict__ o, unsigned short* __restrict__ ob)
{
  const int t = blockIdx.x;
  const int tid = threadIdx.x;
  const int wave = tid >> 6, lane = tid & 63;
  const size_t base = (size_t)t * 512;
  float v0 = a[base + tid] + b[base + tid];
  float v1 = a[base + 256 + tid] + b[base + 256 + tid];
  __shared__ float red[4];
  float s = wred_sum(v0 + v1);
  if (lane == 0) red[wave] = s;
  __syncthreads();
  float mean = (red[0] + red[1] + red[2] + red[3]) * (1.0f / 512.0f);
  float d0 = v0 - mean, d1 = v1 - mean;
  float vs = wred_sum(d0 * d0 + d1 * d1);
  __syncthreads();
  if (lane == 0) red[wave] = vs;
  __syncthreads();
  float var = (red[0] + red[1] + red[2] + red[3]) * (1.0f / 512.0f);
  float rstd = rsqrtf(var + 1e-5f);
  float r0 = d0 * rstd * g[tid] + be[tid];
  float r1 = d1 * rstd * g[256 + tid] + be[256 + tid];
  o[base + tid] = r0;
  o[base + 256 + tid] = r1;
  ob[base + tid] = f2bf(r0);
  ob[base + 256 + tid] = f2bf(r1);
}

// ---------------- embedding builders ----------------
// build_traj: 1 wave = 1 token; every load/store is a coalesced 16B op.
// Id half reads the bf16 transposed table Wwt[51][256] (contiguous row copy,
// L1-resident) instead of gathering fp32 Ww at stride 204B (R6 post-mortem:
// that gather pulled ~64B of line per 4B used and capped the kernel at 1 TB/s).
__global__ __launch_bounds__(256) void build_traj_kernel(
    const float* __restrict__ tf, const int* __restrict__ ids,
    const unsigned short* __restrict__ Wwt, unsigned short* __restrict__ traj)
{
  int idx = blockIdx.x * 256 + threadIdx.x;   // over 57600*64
  int tok = idx >> 6;
  int sub = idx & 63;
  uint4 o;
  if (sub < 32) {
    const float* ip = tf + ((size_t)tok << 8) + sub * 8;
    float4 a = *reinterpret_cast<const float4*>(ip);
    float4 b = *reinterpret_cast<const float4*>(ip + 4);
    o.x = pack2bf(a.x, a.y); o.y = pack2bf(a.z, a.w);
    o.z = pack2bf(b.x, b.y); o.w = pack2bf(b.z, b.w);
  } else {
    int id = ids[tok];
    o = *reinterpret_cast<const uint4*>(Wwt + id * 256 + (sub - 32) * 8);
  }
  *reinterpret_cast<uint4*>(traj + ((size_t)tok << 9) + sub * 8) = o;
}

__global__ __launch_bounds__(256) void build_unk_kernel(
    const float* __restrict__ uf, const float* __restrict__ Ww,
    float* __restrict__ x, unsigned short* __restrict__ xb)
{
  int idx = blockIdx.x * 256 + threadIdx.x;   // over 1920*64
  int tok = idx >> 6;
  int sub = idx & 63;
  float f[8];
  if (sub < 32) {
    const float* ip = uf + ((size_t)tok << 8) + sub * 8;
    float4 a = *reinterpret_cast<const float4*>(ip);
    float4 b = *reinterpret_cast<const float4*>(ip + 4);
    f[0] = a.x; f[1] = a.y; f[2] = a.z; f[3] = a.w;
    f[4] = b.x; f[5] = b.y; f[6] = b.z; f[7] = b.w;
  } else {
    const float* wp = Ww + (size_t)((sub - 32) * 8) * 51 + 50;
#pragma unroll
    for (int e = 0; e < 8; ++e) f[e] = wp[e * 51];
  }
  size_t base = ((size_t)tok << 9) + sub * 8;
  float4 x0 = {f[0], f[1], f[2], f[3]};
  float4 x1 = {f[4], f[5], f[6], f[7]};
  *reinterpret_cast<float4*>(x + base) = x0;
  *reinterpret_cast<float4*>(x + base + 4) = x1;
  uint4 o;
  o.x = pack2bf(f[0], f[1]); o.y = pack2bf(f[2], f[3]);
  o.z = pack2bf(f[4], f[5]); o.w = pack2bf(f[6], f[7]);
  *reinterpret_cast<uint4*>(xb + base) = o;
}

// ---------------- final head ----------------
__global__ __launch_bounds__(64) void head_kernel(
    const float* __restrict__ x, const float* __restrict__ Wout, float* __restrict__ out)
{
  const int t = blockIdx.x;
  const int tid = threadIdx.x;
  __shared__ float xs[256];
  for (int i = tid; i < 256; i += 64) xs[i] = x[(size_t)t * 512 + 256 + i];
  __syncthreads();
  if (tid < 51) {
    const float* w = Wout + tid * 256;
    float s = 0.f;
    for (int k = 0; k < 256; ++k) s = fmaf(xs[k], w[k], s);
    out[t * 51 + tid] = s;
  }
}

// ---------------- orchestration ----------------
extern "C" void kernel_launch(void* const* d_in, const int* in_sizes, int n_in,
                              void* d_out, int out_size, void* d_ws, size_t ws_size,
                              hipStream_t stream) {
  const float* tf  = (const float*)d_in[0];
  const float* uf  = (const float*)d_in[1];
  const int*   ids = (const int*)d_in[2];
  const int*   tt  = (const int*)d_in[3];
  const int*   ut  = (const int*)d_in[4];
  const unsigned char* tm = (const unsigned char*)d_in[5];
  const unsigned char* um = (const unsigned char*)d_in[6];
  const float* Ww   = (const float*)d_in[8];
  const float* Wout = (const float*)d_in[9];
  const float* rpe  = (const float*)d_in[10];
  const float* saW  = (const float*)d_in[11];
  const float* sab  = (const float*)d_in[12];
  const float* saO  = (const float*)d_in[13];
  const float* saob = (const float*)d_in[14];
  const float* sag  = (const float*)d_in[15];
  const float* sabn = (const float*)d_in[16];
  const float* caW  = (const float*)d_in[17];
  const float* cab  = (const float*)d_in[18];
  const float* caO  = (const float*)d_in[19];
  const float* caob = (const float*)d_in[20];
  const float* cag  = (const float*)d_in[21];
  const float* cabn = (const float*)d_in[22];
  const float* f1   = (const float*)d_in[23];
  const float* fb1  = (const float*)d_in[24];
  const float* f2   = (const float*)d_in[25];
  const float* fb2  = (const float*)d_in[26];
  const float* fg   = (const float*)d_in[27];
  const float* fbn  = (const float*)d_in[28];

  // ---- workspace layout ----
  unsigned short* trajb = (unsigned short*)d_ws;         // 57600*512 bf16
  unsigned short* KVb   = trajb + (size_t)29491200;      // 57600*1024 bf16 (K|V token-major)
  unsigned short* qkvb  = KVb   + (size_t)58982400;      // 1920*1536 bf16
  unsigned short* hb    = qkvb  + (size_t)2949120;       // 1920*2048 bf16
  unsigned short* xb    = hb    + (size_t)3932160;       // 1920*512 bf16
  float* x    = (float*)(xb + (size_t)983040);           // 1920*512 fp32
  float* ybuf = x + (size_t)983040;                      // 1920*512 fp32
  unsigned short* wtail = (unsigned short*)(ybuf + (size_t)983040);  // byte 200,540,160

  // pre-converted all-layer weights region (48.2 MB) + 26KB Wwt if ws allows
  const size_t NEED = (size_t)200540160 + (size_t)24117248 * 2 + 32768;
  const bool pre = ws_size >= NEED;
  unsigned short* wsa  = wtail;                          // 5 x 786432  (sa_Wqkv)
  unsigned short* wsaO = wsa  + (size_t)3932160;         // 5 x 262144  (sa_Wo)
  unsigned short* wca  = wsaO + (size_t)1310720;         // 6 x 786432  (ca_Wqkv)
  unsigned short* wcaO = wca  + (size_t)4718592;         // 6 x 262144  (ca_Wo)
  unsigned short* wf1  = wcaO + (size_t)1572864;         // 6 x 1048576 (ffn_W1)
  unsigned short* wf2  = wf1  + (size_t)6291456;         // 6 x 1048576 (ffn_W2)
  unsigned short* Wwt  = wf2  + (size_t)6291456;         // 51 x 256 bf16 id-embed table
  unsigned short* wconv = wtail;                         // fallback rotating scratch (2 MB)
  unsigned short* WwtF  = wconv + (size_t)1048576;       // fallback Wwt location

  if (pre) {
    conv_kernel<<<dim3(3840), dim3(256), 0, stream>>>(saW, wsa, 3932160);
    conv_kernel<<<dim3(1280), dim3(256), 0, stream>>>(saO, wsaO, 1310720);
    conv_kernel<<<dim3(4608), dim3(256), 0, stream>>>(caW, wca, 4718592);
    conv_kernel<<<dim3(1536), dim3(256), 0, stream>>>(caO, wcaO, 1572864);
    conv_kernel<<<dim3(6144), dim3(256), 0, stream>>>(f1, wf1, 6291456);
    conv_kernel<<<dim3(6144), dim3(256), 0, stream>>>(f2, wf2, 6291456);
  }
  unsigned short* wwt = pre ? Wwt : WwtF;
  build_wwt_kernel<<<dim3(51), dim3(256), 0, stream>>>(Ww, wwt);

  build_traj_kernel<<<dim3(14400), dim3(256), 0, stream>>>(tf, ids, wwt, trajb);
  build_unk_kernel<<<dim3(480), dim3(256), 0, stream>>>(uf, Ww, x, xb);

  for (int l = 0; l < 6; ++l) {
    if (l > 0) {
      int sl = l - 1;
      const unsigned short* wq;
      if (pre) wq = wsa + (size_t)sl * 786432;
      else {
        conv_kernel<<<dim3(768), dim3(256), 0, stream>>>(saW + (size_t)sl * 786432, wconv, 786432);
        wq = wconv;
      }
      gemm_mfma<<<dim3(12, 15), dim3(256), 0, stream>>>(
          xb, 512, wq, 512, sab + sl * 1536, qkvb, 1536, 512, 0, 1, 0);
      attn2_kernel<<<dim3(256, 2), dim3(256), 0, stream>>>(
          qkvb, 1536, qkvb + 512, 1536, qkvb + 1024, 1536, hb, 512, 60, um);
      const unsigned short* wo;
      if (pre) wo = wsaO + (size_t)sl * 262144;
      else {
        conv_kernel<<<dim3(256), dim3(256), 0, stream>>>(saO + (size_t)sl * 262144, wconv, 262144);
        wo = wconv;
      }
      gemm_mfma<<<dim3(4, 15), dim3(256), 0, stream>>>(
          hb, 512, wo, 512, saob + sl * 512, ybuf, 512, 512, 0, 0, 0);
      add_ln_kernel<<<dim3(1920), dim3(256), 0, stream>>>(x, ybuf, sag + sl * 512, sabn + sl * 512, x, xb);
    }
    const unsigned short* wqkv;
    if (pre) wqkv = wca + (size_t)l * 786432;
    else {
      conv_kernel<<<dim3(768), dim3(256), 0, stream>>>(caW + (size_t)l * 786432, wconv, 786432);
      wqkv = wconv;
    }
    // cross-attn K|V: [57600,512] @ [1024,512]^T -> [57600,1024] bf16
    gemm256<<<dim3(900), dim3(512), 0, stream>>>(
        trajb, wqkv + 262144, cab + l * 1536 + 512, KVb);
    // cross-attn Q: [1920,512]
    gemm_mfma<<<dim3(4, 15), dim3(256), 0, stream>>>(
        xb, 512, wqkv, 512, cab + l * 1536, qkvb, 512, 512, 0, 1, 0);
    attn_mfma_kernel<<<dim3(256), dim3(512), 0, stream>>>(
        qkvb, KVb, hb, tt, ut, tm, rpe + l * 256);
    const unsigned short* wco;
    if (pre) wco = wcaO + (size_t)l * 262144;
    else {
      conv_kernel<<<dim3(256), dim3(256), 0, stream>>>(caO + (size_t)l * 262144, wconv, 262144);
      wco = wconv;
    }
    gemm_mfma<<<dim3(4, 15), dim3(256), 0, stream>>>(
        hb, 512, wco, 512, caob + l * 512, ybuf, 512, 512, 0, 0, 0);
    add_ln_kernel<<<dim3(1920), dim3(256), 0, stream>>>(x, ybuf, cag + l * 512, cabn + l * 512, x, xb);
    // FFN1 + exact GELU
    const unsigned short* w1;
    if (pre) w1 = wf1 + (size_t)l * 1048576;
    else {
      conv_kernel<<<dim3(1024), dim3(256), 0, stream>>>(f1 + (size_t)l * 1048576, wconv, 1048576);
      w1 = wconv;
    }
    gemm_mfma<<<dim3(16, 15), dim3(256), 0, stream>>>(
        xb, 512, w1, 512, fb1 + l * 2048, hb, 2048, 512, 1, 1, 0);
    // FFN2
    const unsigned short* w2;
    if (pre) w2 = wf2 + (size_t)l * 1048576;
    else {
      conv_kernel<<<dim3(1024), dim3(256), 0, stream>>>(f2 + (size_t)l * 1048576, wconv, 1048576);
      w2 = wconv;
    }
    gemm_mfma<<<dim3(4, 15), dim3(256), 0, stream>>>(
        hb, 2048, w2, 2048, fb2 + l * 512, ybuf, 512, 2048, 0, 0, 0);
    add_ln_kernel<<<dim3(1920), dim3(256), 0, stream>>>(x, ybuf, fg + l * 512, fbn + l * 512, x, xb);
  }
  head_kernel<<<dim3(1920), dim3(64), 0, stream>>>(x, Wout, (float*)d_out);
}

// Round 8
// 1814.113 us; speedup vs baseline: 1.0887x; 1.0515x over previous
//
#include <hip/hip_runtime.h>
#include <cmath>

// ---------------- bf16 helpers ----------------
__device__ __forceinline__ float bflo(unsigned int u) {
  union { unsigned int i; float f; } v; v.i = u << 16; return v.f;
}
__device__ __forceinline__ float bfhi(unsigned int u) {
  union { unsigned int i; float f; } v; v.i = u & 0xffff0000u; return v.f;
}
__device__ __forceinline__ float bf2f(unsigned short u) {
  union { unsigned int i; float f; } v; v.i = ((unsigned int)u) << 16; return v.f;
}
__device__ __forceinline__ unsigned short f2bf(float f) {
  union { float f; unsigned int i; } v; v.f = f;
  unsigned int i = v.i;
  return (unsigned short)((i + 0x7fffu + ((i >> 16) & 1u)) >> 16);  // RNE
}
__device__ __forceinline__ unsigned int pack2bf(float a, float b) {
  return (unsigned int)f2bf(a) | ((unsigned int)f2bf(b) << 16);
}

typedef __attribute__((ext_vector_type(8))) short short8;
typedef __attribute__((ext_vector_type(4))) float floatx4;

// ---------------- fp32 -> bf16 weight conversion ----------------
__global__ __launch_bounds__(256) void conv_kernel(
    const float* __restrict__ in, unsigned short* __restrict__ out, int n)
{
  int i = (blockIdx.x * 256 + threadIdx.x) << 2;
  if (i >= n) return;
  float4 v = *reinterpret_cast<const float4*>(in + i);
  ushort4 o;
  o.x = f2bf(v.x); o.y = f2bf(v.y); o.z = f2bf(v.z); o.w = f2bf(v.w);
  *reinterpret_cast<ushort4*>(out + i) = o;
}

// ---------------- Ww -> bf16 transposed table Wwt[51][256] (runs once) ----------------
__global__ __launch_bounds__(256) void build_wwt_kernel(
    const float* __restrict__ Ww, unsigned short* __restrict__ Wwt)
{
  int c = blockIdx.x;      // vocab id 0..50
  int r = threadIdx.x;     // embed dim 0..255
  Wwt[c * 256 + r] = f2bf(Ww[r * 51 + c]);
}

// ============ 128x256 2-barrier/tile GEMM (KV projection only) ============
// C[M,1024] = A[M,512] @ W[1024,512]^T + bias, bf16 out. M%128==0.
// R7 post-mortem: 256² 8-phase (128KiB LDS, ~240 unified regs) = 1 block/CU;
// 8-wave lockstep across 8 barriers/K-tile left MfmaUtil at 27.6% (measured:
// per-block 25us vs 6.9us MFMA-busy). This shape targets 2 blocks/CU:
// BM=128,BN=256,BK=32; 8 waves of 64x64 (acc 64 f32 -> ~115 regs <=128,
// launch_bounds(512,4)); LDS 2 slots x (A 8KB + B 16KB) = 48KiB;
// 2 barriers/K-tile; depth-2 counted-vmcnt(3) prefetch; T2 slot-swizzle
// key (row>>1)&3 both sides (R4); bijective XCD swizzle (nwg=1800).
__global__ __launch_bounds__(512, 4) void gemm256(
    const unsigned short* __restrict__ A,
    const unsigned short* __restrict__ W,
    const float* __restrict__ bias,
    unsigned short* __restrict__ C)
{
  __shared__ __align__(16) unsigned short LA[2][4096];   // 128 x 32 per slot
  __shared__ __align__(16) unsigned short LB[2][8192];   // 256 x 32 per slot
  const int tid = threadIdx.x;
  const int wave = tid >> 6, lane = tid & 63;
  const int quad = lane >> 4, mrow = lane & 15;
  const int wm = wave >> 2, wn = wave & 3;   // 2M x 4N waves, 64x64 each
  const size_t ldK = 512;
  const int nt = 16;  // K=512 / 32

  // bijective XCD swizzle (nwg=1800, %8==0: q=225); N-fast f for A-panel reuse
  int f = blockIdx.x;
  {
    const int q = gridDim.x >> 3;
    f = (f & 7) * q + (f >> 3);
  }
  const int bn = (f & 3) << 8;
  const int bm = (f >> 2) << 7;

  floatx4 acc[4][4];
#pragma unroll
  for (int i = 0; i < 4; ++i)
#pragma unroll
    for (int j = 0; j < 4; ++j) acc[i][j] = (floatx4){0.f, 0.f, 0.f, 0.f};

  // staging: row = tid/4 (0..127), dest slot = tid&3 (linear, lane x 16B);
  // source slot pre-XOR'd with (row>>1)&3 (B's +128 row offset preserves key).
  const int srow = tid >> 2;
  const int sslot = (tid & 3) ^ ((srow >> 1) & 3);

#define STAGE32(p, kelem)                                                            \
  do {                                                                               \
    __builtin_amdgcn_global_load_lds(                                                \
        (const __attribute__((address_space(1))) unsigned int*)(                     \
            A + (size_t)(bm + srow) * ldK + (kelem) + sslot * 8),                    \
        (__attribute__((address_space(3))) unsigned int*)(&LA[(p)][0] + wave * 512), \
        16, 0, 0);                                                                   \
    __builtin_amdgcn_global_load_lds(                                                \
        (const __attribute__((address_space(1))) unsigned int*)(                     \
            W + (size_t)(bn + srow) * ldK + (kelem) + sslot * 8),                    \
        (__attribute__((address_space(3))) unsigned int*)(&LB[(p)][0] + wave * 512), \
        16, 0, 0);                                                                   \
    __builtin_amdgcn_global_load_lds(                                                \
        (const __attribute__((address_space(1))) unsigned int*)(                     \
            W + (size_t)(bn + 128 + srow) * ldK + (kelem) + sslot * 8),              \
        (__attribute__((address_space(3))) unsigned int*)(&LB[(p)][4096] + wave * 512), \
        16, 0, 0);                                                                   \
  } while (0)

  // prologue: tiles 0 and 1 (3 loads each); wait tile0, keep tile1 in flight
  STAGE32(0, 0);
  STAGE32(1, 32);
  asm volatile("s_waitcnt vmcnt(3)" ::: "memory");
  __builtin_amdgcn_s_barrier();

  const int rsw = ((quad ^ ((mrow >> 1) & 3)) << 3);
  const int arowb = wm * 64 + mrow;
  const int brows = wn * 64 + mrow;

  for (int T = 0; T < nt; ++T) {
    const int p = T & 1;
    short8 afr[4], bfr[4];
#pragma unroll
    for (int i = 0; i < 4; ++i)
      afr[i] = *reinterpret_cast<const short8*>(&LA[p][(arowb + i * 16) * 32 + rsw]);
#pragma unroll
    for (int j = 0; j < 4; ++j)
      bfr[j] = *reinterpret_cast<const short8*>(&LB[p][(brows + j * 16) * 32 + rsw]);
    asm volatile("s_waitcnt lgkmcnt(0)" ::: "memory");
    __builtin_amdgcn_s_barrier();            // all waves drained own reads -> slot p consumed
    if (T + 2 < nt) STAGE32(p, (T + 2) * 32);  // safe: writes a fully-dead region
    __builtin_amdgcn_s_setprio(1);
#pragma unroll
    for (int i = 0; i < 4; ++i)
#pragma unroll
      for (int j = 0; j < 4; ++j)
        acc[i][j] = __builtin_amdgcn_mfma_f32_16x16x32_bf16(afr[i], bfr[j], acc[i][j], 0, 0, 0);
    __builtin_amdgcn_s_setprio(0);
    // tile close: wait (T+1)'s 3 loads (leave (T+2)'s 3 in flight)
    if (T + 2 < nt) asm volatile("s_waitcnt vmcnt(3)" ::: "memory");
    else            asm volatile("s_waitcnt vmcnt(0)" ::: "memory");
    __builtin_amdgcn_s_barrier();            // slot p^1 ready for tile T+1
  }
#undef STAGE32

  const int col0 = lane & 15;
  const int row0 = (lane >> 4) << 2;
#pragma unroll
  for (int i = 0; i < 4; ++i)
#pragma unroll
    for (int j = 0; j < 4; ++j) {
      int col = bn + wn * 64 + j * 16 + col0;
      float bv = bias[col];
#pragma unroll
      for (int r = 0; r < 4; ++r) {
        int row = bm + wm * 64 + i * 16 + row0 + r;
        C[(size_t)row * 1024 + col] = f2bf(acc[i][j][r] + bv);
      }
    }
}

// ---------------- MFMA GEMM: C[M,N] = act(A[M,K] @ W[N,K]^T + bias) ----------------
// 128^2 2-phase counted-vmcnt structure; used for all small GEMMs.
__global__ __launch_bounds__(256) void gemm_mfma(
    const unsigned short* __restrict__ A, int lda,
    const unsigned short* __restrict__ W, int ldw,
    const float* __restrict__ bias,
    void* __restrict__ Cv, int ldc,
    int K, int act, int cbf16, int swz)
{
  __shared__ __align__(16) unsigned short As[2][128 * 32];
  __shared__ __align__(16) unsigned short Bs[2][128 * 32];
  const int tid = threadIdx.x;
  const int wave = tid >> 6, lane = tid & 63;

  int bxi = blockIdx.x, byi = blockIdx.y;
  if (swz) {
    int f = byi * gridDim.x + bxi;
    int q = (gridDim.x * gridDim.y) >> 3;
    f = (f & 7) * q + (f >> 3);
    bxi = f % gridDim.x;
    byi = f / gridDim.x;
  }
  const int bm = byi * 128, bn = bxi * 128;
  const int wm = (wave >> 1) << 6, wn = (wave & 1) << 6;

  floatx4 acc[4][4];
#pragma unroll
  for (int i = 0; i < 4; ++i)
#pragma unroll
    for (int j = 0; j < 4; ++j) acc[i][j] = (floatx4){0.f, 0.f, 0.f, 0.f};

  const int srow = (wave << 5) + (lane >> 2);
  const int chsw = (lane & 3) ^ ((srow >> 1) & 3);
  const int scol = chsw << 3;
  const unsigned short* Ag  = A + (size_t)(bm + srow) * lda + scol;
  const unsigned short* Wg  = W + (size_t)(bn + srow) * ldw + scol;
  const unsigned short* Ag2 = Ag + (size_t)16 * lda;
  const unsigned short* Wg2 = Wg + (size_t)16 * ldw;
  const int ldsw = (wave << 5) * 32;

  const int arow = lane & 15;
  const int rsw  = (arow >> 1) & 3;
  const int chrd = (lane >> 4) ^ rsw;
  const int aoff = (wm + arow) * 32 + (chrd << 3);
  const int boff = (wn + arow) * 32 + (chrd << 3);

  const int nt = K >> 5;

#define STAGE(b, t)                                                                 \
  do {                                                                              \
    const int k0_ = (t) << 5;                                                       \
    __builtin_amdgcn_global_load_lds(                                               \
        (const __attribute__((address_space(1))) unsigned int*)(Ag + k0_),          \
        (__attribute__((address_space(3))) unsigned int*)(As[(b)] + ldsw), 16, 0, 0); \
    __builtin_amdgcn_global_load_lds(                                               \
        (const __attribute__((address_space(1))) unsigned int*)(Ag2 + k0_),         \
        (__attribute__((address_space(3))) unsigned int*)(As[(b)] + ldsw + 16 * 32), 16, 0, 0); \
    __builtin_amdgcn_global_load_lds(                                               \
        (const __attribute__((address_space(1))) unsigned int*)(Wg + k0_),          \
        (__attribute__((address_space(3))) unsigned int*)(Bs[(b)] + ldsw), 16, 0, 0); \
    __builtin_amdgcn_global_load_lds(                                               \
        (const __attribute__((address_space(1))) unsigned int*)(Wg2 + k0_),         \
        (__attribute__((address_space(3))) unsigned int*)(Bs[(b)] + ldsw + 16 * 32), 16, 0, 0); \
  } while (0)

  STAGE(0, 0);
  if (nt > 1) STAGE(1, 1);

  int cur = 0;
  for (int t = 0; t < nt; ++t) {
    if (t + 1 < nt) asm volatile("s_waitcnt vmcnt(4)\n\ts_barrier" ::: "memory");
    else            asm volatile("s_waitcnt vmcnt(0)\n\ts_barrier" ::: "memory");

    short8 af[4], bf[4];
#pragma unroll
    for (int i = 0; i < 4; ++i) {
      af[i] = *reinterpret_cast<const short8*>(&As[cur][aoff + (i << 4) * 32]);
      bf[i] = *reinterpret_cast<const short8*>(&Bs[cur][boff + (i << 4) * 32]);
    }
    asm volatile("s_waitcnt lgkmcnt(0)\n\ts_barrier" ::: "memory");
    if (t + 2 < nt) STAGE(cur, t + 2);

#pragma unroll
    for (int i = 0; i < 4; ++i)
#pragma unroll
      for (int j = 0; j < 4; ++j)
        acc[i][j] = __builtin_amdgcn_mfma_f32_16x16x32_bf16(af[i], bf[j], acc[i][j], 0, 0, 0);
    cur ^= 1;
  }
#undef STAGE

  const int col0 = lane & 15;
  const int row0 = (lane >> 4) << 2;
#pragma unroll
  for (int i = 0; i < 4; ++i) {
#pragma unroll
    for (int j = 0; j < 4; ++j) {
      int col = bn + wn + (j << 4) + col0;
      float bv = bias ? bias[col] : 0.f;
#pragma unroll
      for (int r = 0; r < 4; ++r) {
        int row = bm + wm + (i << 4) + row0 + r;
        float v = acc[i][j][r] + bv;
        if (act) v = 0.5f * v * (1.f + erff(v * 0.70710678f));  // exact GELU
        if (cbf16) ((unsigned short*)Cv)[(size_t)row * ldc + col] = f2bf(v);
        else       ((float*)Cv)[(size_t)row * ldc + col] = v;
      }
    }
  }
}

// ---------------- wave reductions ----------------
__device__ __forceinline__ float wred_max(float v) {
#pragma unroll
  for (int off = 32; off > 0; off >>= 1) v = fmaxf(v, __shfl_xor(v, off, 64));
  return v;
}
__device__ __forceinline__ float wred_sum(float v) {
#pragma unroll
  for (int off = 32; off > 0; off >>= 1) v += __shfl_xor(v, off, 64);
  return v;
}

// ============ MFMA cross-attention (flash, 2 k-groups, in-block merge) ============
#define LDK 72
__global__ __launch_bounds__(512) void attn_mfma_kernel(
    const unsigned short* __restrict__ Qp,   // [bg*60][512] bf16
    const unsigned short* __restrict__ KVb,  // [bg*1800][1024] bf16: K|V
    unsigned short* __restrict__ O,          // [bg*60][512] bf16
    const int* __restrict__ tt, const int* __restrict__ ut,
    const unsigned char* __restrict__ km,
    const float* __restrict__ rel)           // rpe[l]: [32][8]
{
  const int bg = blockIdx.x >> 3, h = blockIdx.x & 7;
  const int tid = threadIdx.x;
  const int grp = tid >> 8;
  const int wave = (tid >> 6) & 3;
  const int lane = tid & 63;
  const int quad = lane >> 4, mrow = lane & 15;

  __shared__ __align__(16) unsigned short SMEM[6 * 64 * LDK];
  unsigned short* Ks = SMEM + grp * (3 * 64 * LDK);
  unsigned short* Vt = Ks + 64 * LDK;
  unsigned short* Ps = Vt + 64 * LDK;

  const int qa = wave * 16 + mrow;
  const int qc = qa < 60 ? qa : 59;
  const unsigned short* qptr = Qp + (size_t)(bg * 60 + qc) * 512 + h * 64 + quad * 8;
  const short8 af0 = *reinterpret_cast<const short8*>(qptr);
  const short8 af1 = *reinterpret_cast<const short8*>(qptr + 32);

  const float relreg = rel[(lane & 31) * 8 + h];

  int tq[4];
  float m[4], l[4];
  floatx4 acc[4];
#pragma unroll
  for (int r = 0; r < 4; ++r) {
    int qo = wave * 16 + quad * 4 + r;
    tq[r] = ut[bg * 60 + (qo < 60 ? qo : 59)];
    m[r] = grp ? -1e30f : 0.f;
    l[r] = grp ? 0.f : 1.f;
  }
#pragma unroll
  for (int nt = 0; nt < 4; ++nt) acc[nt] = (floatx4){0.f, 0.f, 0.f, 0.f};

  const int sk = tid & 255;
  const int stok = sk >> 2, schk = sk & 3;

  for (int it = 0; it < 15; ++it) {
    const int k0 = (grp + 2 * it) << 6;
    __syncthreads();
    {
      const int key = k0 + stok;
      uint4 kr0 = {0,0,0,0}, kr1 = {0,0,0,0}, vr0 = {0,0,0,0}, vr1 = {0,0,0,0};
      if (key < 1800) {
        const unsigned short* kb = KVb + ((size_t)bg * 1800 + key) * 1024 + h * 64 + schk * 16;
        kr0 = *reinterpret_cast<const uint4*>(kb);
        kr1 = *reinterpret_cast<const uint4*>(kb + 8);
        vr0 = *reinterpret_cast<const uint4*>(kb + 512);
        vr1 = *reinterpret_cast<const uint4*>(kb + 520);
      }
      *reinterpret_cast<uint4*>(&Ks[stok * LDK + schk * 16]) = kr0;
      *reinterpret_cast<uint4*>(&Ks[stok * LDK + schk * 16 + 8]) = kr1;
      unsigned int wv[8] = {vr0.x, vr0.y, vr0.z, vr0.w, vr1.x, vr1.y, vr1.z, vr1.w};
#pragma unroll
      for (int e = 0; e < 16; ++e)
        Vt[(schk * 16 + e) * LDK + stok] = (unsigned short)(wv[e >> 1] >> ((e & 1) * 16));
    }
    int meta = 0x10000;
    {
      int kk = k0 + lane;
      if (kk < 1800) {
        int base = bg * 1800 + kk;
        meta = tt[base] | (km[base] ? 0x10000 : 0);
      }
    }
    __syncthreads();

    floatx4 S[4];
#pragma unroll
    for (int nt = 0; nt < 4; ++nt) {
      const unsigned short* kb = Ks + (nt * 16 + mrow) * LDK + quad * 8;
      short8 b0 = *reinterpret_cast<const short8*>(kb);
      short8 b1 = *reinterpret_cast<const short8*>(kb + 32);
      floatx4 s = (floatx4){0.f, 0.f, 0.f, 0.f};
      s = __builtin_amdgcn_mfma_f32_16x16x32_bf16(af0, b0, s, 0, 0, 0);
      s = __builtin_amdgcn_mfma_f32_16x16x32_bf16(af1, b1, s, 0, 0, 0);
      S[nt] = s;
    }
    int mcol[4];
#pragma unroll
    for (int nt = 0; nt < 4; ++nt)
      mcol[nt] = __builtin_amdgcn_ds_bpermute((nt * 16 + mrow) << 2, meta);
    float sv[4][4];
#pragma unroll
    for (int nt = 0; nt < 4; ++nt) {
      int tk = mcol[nt] & 0xffff;
      int bad0 = mcol[nt] >> 16;
#pragma unroll
      for (int r = 0; r < 4; ++r) {
        float v = S[nt][r] * 0.125f;
        int ridx = (tq[r] - tk) & 31;
        v += __int_as_float(__builtin_amdgcn_ds_bpermute(ridx << 2, __float_as_int(relreg)));
        sv[nt][r] = (bad0 | (tk >= tq[r])) ? -1e30f : v;
      }
    }
#pragma unroll
    for (int r = 0; r < 4; ++r) {
      float rm = fmaxf(fmaxf(sv[0][r], sv[1][r]), fmaxf(sv[2][r], sv[3][r]));
#pragma unroll
      for (int d = 1; d < 16; d <<= 1) rm = fmaxf(rm, __shfl_xor(rm, d, 64));
      float nm = fmaxf(m[r], rm);
      float corr = __expf(m[r] - nm);
      float ps = 0.f;
      const int prow = (wave * 16 + quad * 4 + r) * LDK + mrow;
#pragma unroll
      for (int nt = 0; nt < 4; ++nt) {
        float p = __expf(sv[nt][r] - nm);
        ps += p;
        Ps[prow + nt * 16] = f2bf(p);
      }
#pragma unroll
      for (int d = 1; d < 16; d <<= 1) ps += __shfl_xor(ps, d, 64);
      l[r] = l[r] * corr + ps;
      m[r] = nm;
#pragma unroll
      for (int nt = 0; nt < 4; ++nt) acc[nt][r] *= corr;
    }
    const unsigned short* pp = Ps + (wave * 16 + mrow) * LDK + quad * 8;
    short8 a0 = *reinterpret_cast<const short8*>(pp);
    short8 a1 = *reinterpret_cast<const short8*>(pp + 32);
#pragma unroll
    for (int nt = 0; nt < 4; ++nt) {
      const unsigned short* vb = Vt + (nt * 16 + mrow) * LDK + quad * 8;
      short8 b0 = *reinterpret_cast<const short8*>(vb);
      short8 b1 = *reinterpret_cast<const short8*>(vb + 32);
      acc[nt] = __builtin_amdgcn_mfma_f32_16x16x32_bf16(a0, b0, acc[nt], 0, 0, 0);
      acc[nt] = __builtin_amdgcn_mfma_f32_16x16x32_bf16(a1, b1, acc[nt], 0, 0, 0);
    }
  }

  __syncthreads();
  float* MA = (float*)SMEM;
  float* Ml = (float*)(SMEM + 64 * 68 * 2);
  float* Ll = Ml + 64;
  if (grp == 1) {
#pragma unroll
    for (int r = 0; r < 4; ++r) {
      int row = wave * 16 + quad * 4 + r;
#pragma unroll
      for (int nt = 0; nt < 4; ++nt)
        MA[row * 68 + nt * 16 + mrow] = acc[nt][r];
      if (mrow == 0) { Ml[row] = m[r]; Ll[row] = l[r]; }
    }
  }
  __syncthreads();
  if (grp == 0) {
#pragma unroll
    for (int r = 0; r < 4; ++r) {
      int row = wave * 16 + quad * 4 + r;
      float m1 = Ml[row], l1 = Ll[row];
      float M = fmaxf(m[r], m1);
      float c0 = __expf(m[r] - M), c1 = __expf(m1 - M);
      float invL = 1.f / (l[r] * c0 + l1 * c1);
      if (row < 60) {
        unsigned short* op = O + (size_t)(bg * 60 + row) * 512 + h * 64;
#pragma unroll
        for (int nt = 0; nt < 4; ++nt) {
          float o = (acc[nt][r] * c0 + MA[row * 68 + nt * 16 + mrow] * c1) * invL;
          op[nt * 16 + mrow] = f2bf(o);
        }
      }
    }
  }
}

// ---------------- VALU flash attention (self-attn, kLen=60) ----------------
#define QPB 32
#define QPW 8
__global__ __launch_bounds__(256) void attn2_kernel(
    const unsigned short* __restrict__ Qp, int qs,
    const unsigned short* __restrict__ Kp, int ks,
    const unsigned short* __restrict__ Vp, int vs,
    unsigned short* __restrict__ O, int os, int kLen,
    const unsigned char* __restrict__ kmask)
{
  const int bg = blockIdx.x >> 3;
  const int h  = blockIdx.x & 7;
  const int q0 = blockIdx.y * QPB;
  const int tid = threadIdx.x;
  const int wave = tid >> 6, lane = tid & 63;

  __shared__ float Qs[QPB][68];
  __shared__ float Ks[64][68];
  __shared__ float Vs[64][68];
  __shared__ float Ps[QPB][68];

  {
    int qr = tid >> 3, j = tid & 7;
    int q = q0 + qr;
    float f[8] = {0, 0, 0, 0, 0, 0, 0, 0};
    if (q < 60) {
      uint4 v = *reinterpret_cast<const uint4*>(Qp + (size_t)(bg * 60 + q) * qs + h * 64 + j * 8);
      f[0] = bflo(v.x); f[1] = bfhi(v.x); f[2] = bflo(v.y); f[3] = bfhi(v.y);
      f[4] = bflo(v.z); f[5] = bfhi(v.z); f[6] = bflo(v.w); f[7] = bfhi(v.w);
    }
#pragma unroll
    for (int e = 0; e < 8; ++e) Qs[qr][j * 8 + e] = f[e];
  }

  float m[QPW], l[QPW], acc[QPW];
#pragma unroll
  for (int i = 0; i < QPW; ++i) { m[i] = 0.f; l[i] = 1.f; acc[i] = 0.f; }

  const int std = tid >> 2;
  const int stj = tid & 3;

  for (int k0 = 0; k0 < kLen; k0 += 64) {
    __syncthreads();
    const bool sok = (k0 + std) < kLen;
    {
      const unsigned short* kb = Kp + ((size_t)bg * kLen + k0 + std) * ks + h * 64 + stj * 16;
      float f[16];
#pragma unroll
      for (int e = 0; e < 16; ++e) f[e] = 0.f;
      if (sok) {
        uint4 v0 = *reinterpret_cast<const uint4*>(kb);
        uint4 v1 = *reinterpret_cast<const uint4*>(kb + 8);
        f[0] = bflo(v0.x); f[1] = bfhi(v0.x); f[2]  = bflo(v0.y); f[3]  = bfhi(v0.y);
        f[4] = bflo(v0.z); f[5] = bfhi(v0.z); f[6]  = bflo(v0.w); f[7]  = bfhi(v0.w);
        f[8] = bflo(v1.x); f[9] = bfhi(v1.x); f[10] = bflo(v1.y); f[11] = bfhi(v1.y);
        f[12] = bflo(v1.z); f[13] = bfhi(v1.z); f[14] = bflo(v1.w); f[15] = bfhi(v1.w);
      }
#pragma unroll
      for (int e = 0; e < 16; ++e) Ks[stj * 16 + e][std] = f[e];
    }
    {
      const unsigned short* vb = Vp + ((size_t)bg * kLen + k0 + std) * vs + h * 64;
#pragma unroll
      for (int c = 0; c < 2; ++c) {
        int off = c * 32 + stj * 8;
        float f[8] = {0, 0, 0, 0, 0, 0, 0, 0};
        if (sok) {
          uint4 v = *reinterpret_cast<const uint4*>(vb + off);
          f[0] = bflo(v.x); f[1] = bfhi(v.x); f[2] = bflo(v.y); f[3] = bfhi(v.y);
          f[4] = bflo(v.z); f[5] = bfhi(v.z); f[6] = bflo(v.w); f[7] = bfhi(v.w);
        }
#pragma unroll
        for (int e = 0; e < 8; ++e) Vs[std][off + e] = f[e];
      }
    }
    const int kk = k0 + lane;
    const bool kok = kk < kLen;
    unsigned char kmv = 0;
    if (kok && kmask) kmv = kmask[(size_t)bg * kLen + kk];
    __syncthreads();

    float s[QPW];
#pragma unroll
    for (int i = 0; i < QPW; ++i) s[i] = 0.f;
    for (int d = 0; d < 64; ++d) {
      float kv = Ks[d][lane];
#pragma unroll
      for (int i = 0; i < QPW; ++i)
        s[i] = fmaf(Qs[wave * QPW + i][d], kv, s[i]);
    }

    const int kmax = min(64, kLen - k0);
#pragma unroll
    for (int i = 0; i < QPW; ++i) {
      float svv = s[i] * 0.125f;
      if (kmv || !kok) svv = -1e30f;
      float nm = fmaxf(m[i], wred_max(svv));
      float p = __expf(svv - nm);
      float ts = wred_sum(p);
      float corr = __expf(m[i] - nm);
      l[i] = l[i] * corr + ts;
      acc[i] *= corr;
      m[i] = nm;
      Ps[wave * QPW + i][lane] = p;
    }
    for (int k = 0; k < kmax; ++k) {
      float v = Vs[k][lane];
#pragma unroll
      for (int i = 0; i < QPW; ++i)
        acc[i] = fmaf(Ps[wave * QPW + i][k], v, acc[i]);
    }
  }

#pragma unroll
  for (int i = 0; i < QPW; ++i) {
    int q = q0 + wave * QPW + i;
    if (q < 60)
      O[(size_t)(bg * 60 + q) * os + h * 64 + lane] = f2bf(acc[i] / l[i]);
  }
}

// ---------------- residual add + LayerNorm (E=512), dual fp32+bf16 out ----------------
__global__ __launch_bounds__(256) void add_ln_kernel(
    const float* __restrict__ a, const float* __restrict__ b,
    const float* __restrict__ g, const float* __restrict__ be,
    float* __restrict__ o, unsigned short* __restrict__ ob)
{
  const int t = blockIdx.x;
  const int tid = threadIdx.x;
  const int wave = tid >> 6, lane = tid & 63;
  const size_t base = (size_t)t * 512;
  float v0 = a[base + tid] + b[base + tid];
  float v1 = a[base + 256 + tid] + b[base + 256 + tid];
  __shared__ float red[4];
  float s = wred_sum(v0 + v1);
  if (lane == 0) red[wave] = s;
  __syncthreads();
  float mean = (red[0] + red[1] + red[2] + red[3]) * (1.0f / 512.0f);
  float d0 = v0 - mean, d1 = v1 - mean;
  float vs = wred_sum(d0 * d0 + d1 * d1);
  __syncthreads();
  if (lane == 0) red[wave] = vs;
  __syncthreads();
  float var = (red[0] + red[1] + red[2] + red[3]) * (1.0f / 512.0f);
  float rstd = rsqrtf(var + 1e-5f);
  float r0 = d0 * rstd * g[tid] + be[tid];
  float r1 = d1 * rstd * g[256 + tid] + be[256 + tid];
  o[base + tid] = r0;
  o[base + 256 + tid] = r1;
  ob[base + tid] = f2bf(r0);
  ob[base + 256 + tid] = f2bf(r1);
}

// ---------------- embedding builders ----------------
// build_traj: 1 wave = 1 token; every load/store is a coalesced 16B op.
// Id half reads the bf16 transposed table Wwt[51][256] (R6 post-mortem).
__global__ __launch_bounds__(256) void build_traj_kernel(
    const float* __restrict__ tf, const int* __restrict__ ids,
    const unsigned short* __restrict__ Wwt, unsigned short* __restrict__ traj)
{
  int idx = blockIdx.x * 256 + threadIdx.x;   // over 57600*64
  int tok = idx >> 6;
  int sub = idx & 63;
  uint4 o;
  if (sub < 32) {
    const float* ip = tf + ((size_t)tok << 8) + sub * 8;
    float4 a = *reinterpret_cast<const float4*>(ip);
    float4 b = *reinterpret_cast<const float4*>(ip + 4);
    o.x = pack2bf(a.x, a.y); o.y = pack2bf(a.z, a.w);
    o.z = pack2bf(b.x, b.y); o.w = pack2bf(b.z, b.w);
  } else {
    int id = ids[tok];
    o = *reinterpret_cast<const uint4*>(Wwt + id * 256 + (sub - 32) * 8);
  }
  *reinterpret_cast<uint4*>(traj + ((size_t)tok << 9) + sub * 8) = o;
}

__global__ __launch_bounds__(256) void build_unk_kernel(
    const float* __restrict__ uf, const float* __restrict__ Ww,
    float* __restrict__ x, unsigned short* __restrict__ xb)
{
  int idx = blockIdx.x * 256 + threadIdx.x;   // over 1920*64
  int tok = idx >> 6;
  int sub = idx & 63;
  float f[8];
  if (sub < 32) {
    const float* ip = uf + ((size_t)tok << 8) + sub * 8;
    float4 a = *reinterpret_cast<const float4*>(ip);
    float4 b = *reinterpret_cast<const float4*>(ip + 4);
    f[0] = a.x; f[1] = a.y; f[2] = a.z; f[3] = a.w;
    f[4] = b.x; f[5] = b.y; f[6] = b.z; f[7] = b.w;
  } else {
    const float* wp = Ww + (size_t)((sub - 32) * 8) * 51 + 50;
#pragma unroll
    for (int e = 0; e < 8; ++e) f[e] = wp[e * 51];
  }
  size_t base = ((size_t)tok << 9) + sub * 8;
  float4 x0 = {f[0], f[1], f[2], f[3]};
  float4 x1 = {f[4], f[5], f[6], f[7]};
  *reinterpret_cast<float4*>(x + base) = x0;
  *reinterpret_cast<float4*>(x + base + 4) = x1;
  uint4 o;
  o.x = pack2bf(f[0], f[1]); o.y = pack2bf(f[2], f[3]);
  o.z = pack2bf(f[4], f[5]); o.w = pack2bf(f[6], f[7]);
  *reinterpret_cast<uint4*>(xb + base) = o;
}

// ---------------- final head ----------------
__global__ __launch_bounds__(64) void head_kernel(
    const float* __restrict__ x, const float* __restrict__ Wout, float* __restrict__ out)
{
  const int t = blockIdx.x;
  const int tid = threadIdx.x;
  __shared__ float xs[256];
  for (int i = tid; i < 256; i += 64) xs[i] = x[(size_t)t * 512 + 256 + i];
  __syncthreads();
  if (tid < 51) {
    const float* w = Wout + tid * 256;
    float s = 0.f;
    for (int k = 0; k < 256; ++k) s = fmaf(xs[k], w[k], s);
    out[t * 51 + tid] = s;
  }
}

// ---------------- orchestration ----------------
extern "C" void kernel_launch(void* const* d_in, const int* in_sizes, int n_in,
                              void* d_out, int out_size, void* d_ws, size_t ws_size,
                              hipStream_t stream) {
  const float* tf  = (const float*)d_in[0];
  const float* uf  = (const float*)d_in[1];
  const int*   ids = (const int*)d_in[2];
  const int*   tt  = (const int*)d_in[3];
  const int*   ut  = (const int*)d_in[4];
  const unsigned char* tm = (const unsigned char*)d_in[5];
  const unsigned char* um = (const unsigned char*)d_in[6];
  const float* Ww   = (const float*)d_in[8];
  const float* Wout = (const float*)d_in[9];
  const float* rpe  = (const float*)d_in[10];
  const float* saW  = (const float*)d_in[11];
  const float* sab  = (const float*)d_in[12];
  const float* saO  = (const float*)d_in[13];
  const float* saob = (const float*)d_in[14];
  const float* sag  = (const float*)d_in[15];
  const float* sabn = (const float*)d_in[16];
  const float* caW  = (const float*)d_in[17];
  const float* cab  = (const float*)d_in[18];
  const float* caO  = (const float*)d_in[19];
  const float* caob = (const float*)d_in[20];
  const float* cag  = (const float*)d_in[21];
  const float* cabn = (const float*)d_in[22];
  const float* f1   = (const float*)d_in[23];
  const float* fb1  = (const float*)d_in[24];
  const float* f2   = (const float*)d_in[25];
  const float* fb2  = (const float*)d_in[26];
  const float* fg   = (const float*)d_in[27];
  const float* fbn  = (const float*)d_in[28];

  // ---- workspace layout ----
  unsigned short* trajb = (unsigned short*)d_ws;         // 57600*512 bf16
  unsigned short* KVb   = trajb + (size_t)29491200;      // 57600*1024 bf16 (K|V token-major)
  unsigned short* qkvb  = KVb   + (size_t)58982400;      // 1920*1536 bf16
  unsigned short* hb    = qkvb  + (size_t)2949120;       // 1920*2048 bf16
  unsigned short* xb    = hb    + (size_t)3932160;       // 1920*512 bf16
  float* x    = (float*)(xb + (size_t)983040);           // 1920*512 fp32
  float* ybuf = x + (size_t)983040;                      // 1920*512 fp32
  unsigned short* wtail = (unsigned short*)(ybuf + (size_t)983040);  // byte 200,540,160

  // pre-converted all-layer weights region (48.2 MB) + 26KB Wwt if ws allows
  const size_t NEED = (size_t)200540160 + (size_t)24117248 * 2 + 32768;
  const bool pre = ws_size >= NEED;
  unsigned short* wsa  = wtail;                          // 5 x 786432  (sa_Wqkv)
  unsigned short* wsaO = wsa  + (size_t)3932160;         // 5 x 262144  (sa_Wo)
  unsigned short* wca  = wsaO + (size_t)1310720;         // 6 x 786432  (ca_Wqkv)
  unsigned short* wcaO = wca  + (size_t)4718592;         // 6 x 262144  (ca_Wo)
  unsigned short* wf1  = wcaO + (size_t)1572864;         // 6 x 1048576 (ffn_W1)
  unsigned short* wf2  = wf1  + (size_t)6291456;         // 6 x 1048576 (ffn_W2)
  unsigned short* Wwt  = wf2  + (size_t)6291456;         // 51 x 256 bf16 id-embed table
  unsigned short* wconv = wtail;                         // fallback rotating scratch (2 MB)
  unsigned short* WwtF  = wconv + (size_t)1048576;       // fallback Wwt location

  if (pre) {
    conv_kernel<<<dim3(3840), dim3(256), 0, stream>>>(saW, wsa, 3932160);
    conv_kernel<<<dim3(1280), dim3(256), 0, stream>>>(saO, wsaO, 1310720);
    conv_kernel<<<dim3(4608), dim3(256), 0, stream>>>(caW, wca, 4718592);
    conv_kernel<<<dim3(1536), dim3(256), 0, stream>>>(caO, wcaO, 1572864);
    conv_kernel<<<dim3(6144), dim3(256), 0, stream>>>(f1, wf1, 6291456);
    conv_kernel<<<dim3(6144), dim3(256), 0, stream>>>(f2, wf2, 6291456);
  }
  unsigned short* wwt = pre ? Wwt : WwtF;
  build_wwt_kernel<<<dim3(51), dim3(256), 0, stream>>>(Ww, wwt);

  build_traj_kernel<<<dim3(14400), dim3(256), 0, stream>>>(tf, ids, wwt, trajb);
  build_unk_kernel<<<dim3(480), dim3(256), 0, stream>>>(uf, Ww, x, xb);

  for (int l = 0; l < 6; ++l) {
    if (l > 0) {
      int sl = l - 1;
      const unsigned short* wq;
      if (pre) wq = wsa + (size_t)sl * 786432;
      else {
        conv_kernel<<<dim3(768), dim3(256), 0, stream>>>(saW + (size_t)sl * 786432, wconv, 786432);
        wq = wconv;
      }
      gemm_mfma<<<dim3(12, 15), dim3(256), 0, stream>>>(
          xb, 512, wq, 512, sab + sl * 1536, qkvb, 1536, 512, 0, 1, 0);
      attn2_kernel<<<dim3(256, 2), dim3(256), 0, stream>>>(
          qkvb, 1536, qkvb + 512, 1536, qkvb + 1024, 1536, hb, 512, 60, um);
      const unsigned short* wo;
      if (pre) wo = wsaO + (size_t)sl * 262144;
      else {
        conv_kernel<<<dim3(256), dim3(256), 0, stream>>>(saO + (size_t)sl * 262144, wconv, 262144);
        wo = wconv;
      }
      gemm_mfma<<<dim3(4, 15), dim3(256), 0, stream>>>(
          hb, 512, wo, 512, saob + sl * 512, ybuf, 512, 512, 0, 0, 0);
      add_ln_kernel<<<dim3(1920), dim3(256), 0, stream>>>(x, ybuf, sag + sl * 512, sabn + sl * 512, x, xb);
    }
    const unsigned short* wqkv;
    if (pre) wqkv = wca + (size_t)l * 786432;
    else {
      conv_kernel<<<dim3(768), dim3(256), 0, stream>>>(caW + (size_t)l * 786432, wconv, 786432);
      wqkv = wconv;
    }
    // cross-attn K|V: [57600,512] @ [1024,512]^T -> [57600,1024] bf16
    // 128x256 tiles: 450 M x 4 N = 1800 blocks, 2 blocks/CU target
    gemm256<<<dim3(1800), dim3(512), 0, stream>>>(
        trajb, wqkv + 262144, cab + l * 1536 + 512, KVb);
    // cross-attn Q: [1920,512]
    gemm_mfma<<<dim3(4, 15), dim3(256), 0, stream>>>(
        xb, 512, wqkv, 512, cab + l * 1536, qkvb, 512, 512, 0, 1, 0);
    attn_mfma_kernel<<<dim3(256), dim3(512), 0, stream>>>(
        qkvb, KVb, hb, tt, ut, tm, rpe + l * 256);
    const unsigned short* wco;
    if (pre) wco = wcaO + (size_t)l * 262144;
    else {
      conv_kernel<<<dim3(256), dim3(256), 0, stream>>>(caO + (size_t)l * 262144, wconv, 262144);
      wco = wconv;
    }
    gemm_mfma<<<dim3(4, 15), dim3(256), 0, stream>>>(
        hb, 512, wco, 512, caob + l * 512, ybuf, 512, 512, 0, 0, 0);
    add_ln_kernel<<<dim3(1920), dim3(256), 0, stream>>>(x, ybuf, cag + l * 512, cabn + l * 512, x, xb);
    // FFN1 + exact GELU
    const unsigned short* w1;
    if (pre) w1 = wf1 + (size_t)l * 1048576;
    else {
      conv_kernel<<<dim3(1024), dim3(256), 0, stream>>>(f1 + (size_t)l * 1048576, wconv, 1048576);
      w1 = wconv;
    }
    gemm_mfma<<<dim3(16, 15), dim3(256), 0, stream>>>(
        xb, 512, w1, 512, fb1 + l * 2048, hb, 2048, 512, 1, 1, 0);
    // FFN2
    const unsigned short* w2;
    if (pre) w2 = wf2 + (size_t)l * 1048576;
    else {
      conv_kernel<<<dim3(1024), dim3(256), 0, stream>>>(f2 + (size_t)l * 1048576, wconv, 1048576);
      w2 = wconv;
    }
    gemm_mfma<<<dim3(4, 15), dim3(256), 0, stream>>>(
        hb, 2048, w2, 2048, fb2 + l * 512, ybuf, 512, 2048, 0, 0, 0);
    add_ln_kernel<<<dim3(1920), dim3(256), 0, stream>>>(x, ybuf, fg + l * 512, fbn + l * 512, x, xb);
  }
  head_kernel<<<dim3(1920), dim3(64), 0, stream>>>(x, Wout, (float*)d_out);
}